// Round 2
// baseline (599.265 us; speedup 1.0000x reference)
//
#include <hip/hip_runtime.h>
#include <hip/hip_bf16.h>

typedef unsigned short u16;
typedef __attribute__((ext_vector_type(8))) short short8;
typedef __attribute__((ext_vector_type(4))) float floatx4;

#define B_SZ 4
#define T_SZ 2048
#define C_SZ 1024
#define NH_SZ 16
#define HD_SZ 64
#define M_TOT 8192      // B*T
#define K_DIM 1024      // C

// workspace layout (u16 element offsets from ws base; all 16B-aligned)
#define OFF_XB   ((size_t)16)
#define OFF_WQT  (OFF_XB + 8388608)
#define OFF_WPT  (OFF_WQT + 3145728)
#define OFF_PB   (OFF_WPT + 1048576)
#define OFF_Q    (OFF_PB + 8192)
#define OFF_K    (OFF_Q + 8388608)
#define OFF_V    (OFF_K + 8388608)
#define OFF_Y    (OFF_V + 8388608)
// params sub-layout inside PB
#define PB_BQKV  0
#define PB_BPROJ 3072
#define PB_QSC   4096
#define PB_QBI   5120
#define PB_KSC   6144
#define PB_KBI   7168

__device__ __forceinline__ float bf2f(u16 u) {
    return __uint_as_float(((unsigned)u) << 16);
}
__device__ __forceinline__ u16 f2bf(float f) {
    unsigned x = __float_as_uint(f);
    unsigned r = (x + 0x7fffu + ((x >> 16) & 1u)) >> 16;
    return (u16)r;
}

// ---- dtype detector: fp32 reinterpreted as bf16 has wild exponents --------
__global__ __launch_bounds__(256) void detect_k(const u16* __restrict__ x,
                                                int* __restrict__ flag) {
    __shared__ int cnt;
    if (threadIdx.x == 0) cnt = 0;
    __syncthreads();
    int bad = 0;
    for (int i = threadIdx.x; i < 512; i += 256) {
        float v = fabsf(bf2f(x[i]));
        if (v > 1024.0f || (v != 0.0f && v < 9.5367431640625e-7f)) bad++;
    }
    atomicAdd(&cnt, bad);
    __syncthreads();
    if (threadIdx.x == 0) flag[0] = (cnt > 16) ? 1 : 0;
}

// ---- normalize any input buffer to bf16 (copy or fp32->bf16) --------------
__global__ __launch_bounds__(256) void conv_copy_k(const void* __restrict__ in,
                                                   u16* __restrict__ out, int n4,
                                                   const int* __restrict__ flag) {
    const int i = blockIdx.x * 256 + threadIdx.x;   // group of 4 elements
    if (i >= n4) return;
    if (flag[0]) {
        const float4 v = ((const float4*)in)[i];
        ushort4 o;
        o.x = f2bf(v.x); o.y = f2bf(v.y); o.z = f2bf(v.z); o.w = f2bf(v.w);
        ((ushort4*)out)[i] = o;
    } else {
        ((ushort4*)out)[i] = ((const ushort4*)in)[i];
    }
}

// ---- weight transpose with dtype normalization: in [R][C] -> out [C][R] ---
__global__ __launch_bounds__(256) void conv_transpose_k(const void* __restrict__ in,
                                                        u16* __restrict__ out,
                                                        int R, int C,
                                                        const int* __restrict__ flag) {
    __shared__ u16 t[32][33];
    const int isf = flag[0];
    const int c0 = blockIdx.x * 32, r0 = blockIdx.y * 32;
    const int tx = threadIdx.x & 31, ty = threadIdx.x >> 5;  // ty in 0..7
    for (int i = 0; i < 4; i++) {
        int r = ty + i * 8;
        size_t idx = (size_t)(r0 + r) * C + c0 + tx;
        t[r][tx] = isf ? f2bf(((const float*)in)[idx]) : ((const u16*)in)[idx];
    }
    __syncthreads();
    for (int i = 0; i < 4; i++) {
        int cr = ty + i * 8;
        out[(size_t)(c0 + cr) * R + r0 + tx] = t[tx][cr];
    }
}

// ---------------- QKV GEMM: X[8192,1024] @ Wt[3072,1024]^T + bias ----------
// epilogue: per-head affine on q/k sections; scatter to [B,NH,T,HD]
__global__ __launch_bounds__(256) void qkv_gemm(
        const u16* __restrict__ X, const u16* __restrict__ Wt,
        const u16* __restrict__ pb,
        u16* __restrict__ Qb, u16* __restrict__ Kb, u16* __restrict__ Vb) {
    __shared__ __align__(16) u16 As[128 * 40];
    __shared__ __align__(16) u16 Bs[128 * 40];
    const int bm = blockIdx.y * 128, bn = blockIdx.x * 128;
    const int tid = threadIdx.x;
    const int lane = tid & 63, wave = tid >> 6;
    const int quad = lane >> 4, l16 = lane & 15;
    const int wm = (wave & 1) * 64, wn = (wave >> 1) * 64;

    floatx4 acc[4][4];
    for (int mi = 0; mi < 4; mi++)
        for (int ni = 0; ni < 4; ni++) acc[mi][ni] = 0.f;

    for (int k0 = 0; k0 < K_DIM; k0 += 32) {
        __syncthreads();
        for (int i = 0; i < 2; i++) {
            int cc = tid + i * 256;           // 512 chunks of 8 elements
            int r = cc >> 2, c8 = (cc & 3) * 8;
            *(float4*)&As[r * 40 + c8] =
                *(const float4*)&X[(size_t)(bm + r) * K_DIM + k0 + c8];
            *(float4*)&Bs[r * 40 + c8] =
                *(const float4*)&Wt[(size_t)(bn + r) * K_DIM + k0 + c8];
        }
        __syncthreads();
        short8 a[4], b[4];
        for (int mi = 0; mi < 4; mi++)
            a[mi] = *(const short8*)&As[(wm + mi * 16 + l16) * 40 + quad * 8];
        for (int ni = 0; ni < 4; ni++)
            b[ni] = *(const short8*)&Bs[(wn + ni * 16 + l16) * 40 + quad * 8];
        for (int mi = 0; mi < 4; mi++)
            for (int ni = 0; ni < 4; ni++)
                acc[mi][ni] = __builtin_amdgcn_mfma_f32_16x16x32_bf16(
                    a[mi], b[ni], acc[mi][ni], 0, 0, 0);
    }

    const int sec = bn >> 10;  // 0=q 1=k 2=v (128-tile never crosses 1024)
    for (int mi = 0; mi < 4; mi++) {
        for (int ni = 0; ni < 4; ni++) {
            const int col = bn + wn + ni * 16 + l16;
            const int cmod = col & 1023;
            const int h = cmod >> 6, d = cmod & 63;
            const float bv = bf2f(pb[PB_BQKV + col]);
            float sA = 1.f, sB = 0.f;
            if (sec == 0) { sA = bf2f(pb[PB_QSC + h * 64 + d]); sB = bf2f(pb[PB_QBI + h * 64 + d]); }
            else if (sec == 1) { sA = bf2f(pb[PB_KSC + h * 64 + d]); sB = bf2f(pb[PB_KBI + h * 64 + d]); }
            u16* dstbuf = (sec == 0) ? Qb : (sec == 1) ? Kb : Vb;
            for (int r = 0; r < 4; r++) {
                const int row = bm + wm + mi * 16 + quad * 4 + r;
                const int bb = row >> 11, t = row & 2047;
                float v = acc[mi][ni][r] + bv;
                if (sec < 2) v = v * sA + sB;
                dstbuf[(((size_t)(bb * NH_SZ + h)) * T_SZ + t) * HD_SZ + d] = f2bf(v);
            }
        }
    }
}

// ---------------- Flash attention: block = (b, h, 64-row q tile) -----------
__global__ __launch_bounds__(256) void attn_k(const u16* __restrict__ Qb,
                                              const u16* __restrict__ Kb,
                                              const u16* __restrict__ Vb,
                                              u16* __restrict__ Y) {
    __shared__ __align__(16) u16 Qs[64 * 72];
    __shared__ __align__(16) u16 Ks[64 * 72];
    __shared__ __align__(16) u16 Vt[64 * 72];       // [d][key]
    __shared__ __align__(16) u16 Ps[4 * 16 * 72];   // per-wave [row][key]
    const int blk = blockIdx.x;
    const int qt = blk & 31, h = (blk >> 5) & 15, b = blk >> 9;
    const int q0 = qt * 64;
    const int tid = threadIdx.x, lane = tid & 63, w = tid >> 6;
    const int quad = lane >> 4, l16 = lane & 15;
    const size_t headoff = ((size_t)(b * NH_SZ + h)) * T_SZ * HD_SZ;

    for (int i = 0; i < 2; i++) {
        int cc = tid + i * 256;
        int r = cc >> 3, c8 = (cc & 7) * 8;
        *(float4*)&Qs[r * 72 + c8] =
            *(const float4*)&Qb[headoff + (size_t)(q0 + r) * HD_SZ + c8];
    }

    floatx4 o[4];
    for (int ni = 0; ni < 4; ni++) o[ni] = 0.f;
    float mreg[4] = {-1e30f, -1e30f, -1e30f, -1e30f};
    float lreg[4] = {0.f, 0.f, 0.f, 0.f};
    const float LOG2E = 1.4426950408889634f;

    for (int k0 = 0; k0 <= q0; k0 += 64) {
        __syncthreads();
        for (int i = 0; i < 2; i++) {
            int cc = tid + i * 256;
            int r = cc >> 3, c8 = (cc & 7) * 8;
            *(float4*)&Ks[r * 72 + c8] =
                *(const float4*)&Kb[headoff + (size_t)(k0 + r) * HD_SZ + c8];
            float4 vv = *(const float4*)&Vb[headoff + (size_t)(k0 + r) * HD_SZ + c8];
            const u16* vs = (const u16*)&vv;
            for (int j = 0; j < 8; j++) Vt[(c8 + j) * 72 + r] = vs[j];
        }
        __syncthreads();

        floatx4 s[4];
        for (int ni = 0; ni < 4; ni++) s[ni] = 0.f;
        for (int kk = 0; kk < 64; kk += 32) {
            short8 a = *(const short8*)&Qs[(w * 16 + l16) * 72 + kk + quad * 8];
            for (int ni = 0; ni < 4; ni++) {
                short8 bfr = *(const short8*)&Ks[(ni * 16 + l16) * 72 + kk + quad * 8];
                s[ni] = __builtin_amdgcn_mfma_f32_16x16x32_bf16(a, bfr, s[ni], 0, 0, 0);
            }
        }

        const float sc = 0.125f;  // 1/sqrt(64)
        if (k0 == q0) {
            for (int ni = 0; ni < 4; ni++)
                for (int r = 0; r < 4; r++) {
                    int row = w * 16 + quad * 4 + r;
                    int col = ni * 16 + l16;
                    s[ni][r] = (col <= row) ? s[ni][r] * sc : -1e30f;
                }
        } else {
            for (int ni = 0; ni < 4; ni++)
                for (int r = 0; r < 4; r++) s[ni][r] *= sc;
        }

        for (int r = 0; r < 4; r++) {
            float rmax = fmaxf(fmaxf(s[0][r], s[1][r]), fmaxf(s[2][r], s[3][r]));
            for (int off = 1; off < 16; off <<= 1)
                rmax = fmaxf(rmax, __shfl_xor(rmax, off, 64));
            const float mold = mreg[r];
            const float mnew = fmaxf(mold, rmax);
            const float alpha = exp2f((mold - mnew) * LOG2E);
            float rsum = 0.f;
            for (int ni = 0; ni < 4; ni++) {
                float pv = exp2f((s[ni][r] - mnew) * LOG2E);
                s[ni][r] = pv;
                rsum += pv;
            }
            for (int off = 1; off < 16; off <<= 1)
                rsum += __shfl_xor(rsum, off, 64);
            mreg[r] = mnew;
            lreg[r] = lreg[r] * alpha + rsum;
            for (int ni = 0; ni < 4; ni++) o[ni][r] *= alpha;
        }

        for (int ni = 0; ni < 4; ni++)
            for (int r = 0; r < 4; r++)
                Ps[w * 1152 + (quad * 4 + r) * 72 + ni * 16 + l16] = f2bf(s[ni][r]);
        __syncthreads();

        for (int kk = 0; kk < 64; kk += 32) {
            short8 a = *(const short8*)&Ps[w * 1152 + l16 * 72 + kk + quad * 8];
            for (int ni = 0; ni < 4; ni++) {
                short8 bfr = *(const short8*)&Vt[(ni * 16 + l16) * 72 + kk + quad * 8];
                o[ni] = __builtin_amdgcn_mfma_f32_16x16x32_bf16(a, bfr, o[ni], 0, 0, 0);
            }
        }
    }

    // write y in [B,T,NH,HD] (= [B,T,C]) layout
    for (int r = 0; r < 4; r++) {
        const int row = q0 + w * 16 + quad * 4 + r;
        const float inv = 1.0f / lreg[r];
        for (int ni = 0; ni < 4; ni++) {
            Y[(((size_t)b * T_SZ + row) * NH_SZ + h) * HD_SZ + ni * 16 + l16] =
                f2bf(o[ni][r] * inv);
        }
    }
}

// ---------------- Proj GEMM: Y[8192,1024] @ Wt[1024,1024]^T + bias ---------
// output dtype branches on flag: fp32 (float*) or bf16 (u16*)
__global__ __launch_bounds__(256) void proj_gemm(const u16* __restrict__ Yin,
                                                 const u16* __restrict__ Wt,
                                                 const u16* __restrict__ pb,
                                                 void* __restrict__ out,
                                                 const int* __restrict__ flag) {
    __shared__ __align__(16) u16 As[128 * 40];
    __shared__ __align__(16) u16 Bs[128 * 40];
    const int isf = flag[0];
    const int bm = blockIdx.y * 128, bn = blockIdx.x * 128;
    const int tid = threadIdx.x;
    const int lane = tid & 63, wave = tid >> 6;
    const int quad = lane >> 4, l16 = lane & 15;
    const int wm = (wave & 1) * 64, wn = (wave >> 1) * 64;

    floatx4 acc[4][4];
    for (int mi = 0; mi < 4; mi++)
        for (int ni = 0; ni < 4; ni++) acc[mi][ni] = 0.f;

    for (int k0 = 0; k0 < K_DIM; k0 += 32) {
        __syncthreads();
        for (int i = 0; i < 2; i++) {
            int cc = tid + i * 256;
            int r = cc >> 2, c8 = (cc & 3) * 8;
            *(float4*)&As[r * 40 + c8] =
                *(const float4*)&Yin[(size_t)(bm + r) * K_DIM + k0 + c8];
            *(float4*)&Bs[r * 40 + c8] =
                *(const float4*)&Wt[(size_t)(bn + r) * K_DIM + k0 + c8];
        }
        __syncthreads();
        short8 a[4], b[4];
        for (int mi = 0; mi < 4; mi++)
            a[mi] = *(const short8*)&As[(wm + mi * 16 + l16) * 40 + quad * 8];
        for (int ni = 0; ni < 4; ni++)
            b[ni] = *(const short8*)&Bs[(wn + ni * 16 + l16) * 40 + quad * 8];
        for (int mi = 0; mi < 4; mi++)
            for (int ni = 0; ni < 4; ni++)
                acc[mi][ni] = __builtin_amdgcn_mfma_f32_16x16x32_bf16(
                    a[mi], b[ni], acc[mi][ni], 0, 0, 0);
    }

    for (int mi = 0; mi < 4; mi++) {
        for (int ni = 0; ni < 4; ni++) {
            const int col = bn + wn + ni * 16 + l16;
            const float bv = bf2f(pb[PB_BPROJ + col]);
            for (int r = 0; r < 4; r++) {
                const int row = bm + wm + mi * 16 + quad * 4 + r;
                const float v = acc[mi][ni][r] + bv;
                if (isf) ((float*)out)[(size_t)row * C_SZ + col] = v;
                else     ((u16*)out)[(size_t)row * C_SZ + col] = f2bf(v);
            }
        }
    }
}

extern "C" void kernel_launch(void* const* d_in, const int* in_sizes, int n_in,
                              void* d_out, int out_size, void* d_ws, size_t ws_size,
                              hipStream_t stream) {
    const void* x     = d_in[0];
    const void* Wqkv  = d_in[1];
    const void* bqkv  = d_in[2];
    const void* Wproj = d_in[3];
    const void* bproj = d_in[4];
    const void* qsc   = d_in[5];
    const void* qbi   = d_in[6];
    const void* ksc   = d_in[7];
    const void* kbi   = d_in[8];

    u16* ws = (u16*)d_ws;
    int* flag    = (int*)d_ws;
    u16* xb      = ws + OFF_XB;
    u16* Wt_qkv  = ws + OFF_WQT;
    u16* Wt_proj = ws + OFF_WPT;
    u16* pb      = ws + OFF_PB;
    u16* Qb      = ws + OFF_Q;
    u16* Kb      = ws + OFF_K;
    u16* Vb      = ws + OFF_V;
    u16* Yb      = ws + OFF_Y;

    detect_k<<<1, 256, 0, stream>>>((const u16*)x, flag);

    conv_copy_k<<<8192, 256, 0, stream>>>(x, xb, 2097152, flag);
    conv_copy_k<<<3, 256, 0, stream>>>(bqkv, pb + PB_BQKV, 768, flag);
    conv_copy_k<<<1, 256, 0, stream>>>(bproj, pb + PB_BPROJ, 256, flag);
    conv_copy_k<<<1, 256, 0, stream>>>(qsc, pb + PB_QSC, 256, flag);
    conv_copy_k<<<1, 256, 0, stream>>>(qbi, pb + PB_QBI, 256, flag);
    conv_copy_k<<<1, 256, 0, stream>>>(ksc, pb + PB_KSC, 256, flag);
    conv_copy_k<<<1, 256, 0, stream>>>(kbi, pb + PB_KBI, 256, flag);
    conv_transpose_k<<<dim3(96, 32), 256, 0, stream>>>(Wqkv, Wt_qkv, 1024, 3072, flag);
    conv_transpose_k<<<dim3(32, 32), 256, 0, stream>>>(Wproj, Wt_proj, 1024, 1024, flag);

    qkv_gemm<<<dim3(24, 64), 256, 0, stream>>>(xb, Wt_qkv, pb, Qb, Kb, Vb);
    attn_k<<<dim3(2048), 256, 0, stream>>>(Qb, Kb, Vb, Yb);
    proj_gemm<<<dim3(8, 64), 256, 0, stream>>>(Yb, Wt_proj, pb, d_out, flag);
}

// Round 3
// 505.682 us; speedup vs baseline: 1.1851x; 1.1851x over previous
//
#include <hip/hip_runtime.h>
#include <hip/hip_bf16.h>

typedef unsigned short u16;
typedef __attribute__((ext_vector_type(8))) short short8;
typedef __attribute__((ext_vector_type(4))) short short4_t;
typedef __attribute__((ext_vector_type(4))) float floatx4;

#define B_SZ 4
#define T_SZ 2048
#define C_SZ 1024
#define NH_SZ 16
#define HD_SZ 64
#define M_TOT 8192      // B*T
#define K_DIM 1024      // C

// fold softmax 1/sqrt(64) and log2(e) into Q's affine: scores land in log2 domain
#define QSCALE 0.1803368801111204f   // 0.125 * 1.4426950408889634

// workspace layout (u16 element offsets from ws base; all 16B-aligned)
#define OFF_XB   ((size_t)16)
#define OFF_WQT  (OFF_XB + 8388608)
#define OFF_WPT  (OFF_WQT + 3145728)
#define OFF_PB   (OFF_WPT + 1048576)
#define OFF_Q    (OFF_PB + 8192)
#define OFF_K    (OFF_Q + 8388608)
#define OFF_V    (OFF_K + 8388608)
#define OFF_Y    (OFF_V + 8388608)
// params sub-layout inside PB
#define PB_BQKV  0
#define PB_BPROJ 3072
#define PB_QSC   4096
#define PB_QBI   5120
#define PB_KSC   6144
#define PB_KBI   7168

__device__ __forceinline__ float bf2f(u16 u) {
    return __uint_as_float(((unsigned)u) << 16);
}
__device__ __forceinline__ u16 f2bf(float f) {
    unsigned x = __float_as_uint(f);
    unsigned r = (x + 0x7fffu + ((x >> 16) & 1u)) >> 16;
    return (u16)r;
}

// ---- dtype detector: fp32 reinterpreted as bf16 has wild exponents --------
__global__ __launch_bounds__(256) void detect_k(const u16* __restrict__ x,
                                                int* __restrict__ flag) {
    __shared__ int cnt;
    if (threadIdx.x == 0) cnt = 0;
    __syncthreads();
    int bad = 0;
    for (int i = threadIdx.x; i < 512; i += 256) {
        float v = fabsf(bf2f(x[i]));
        if (v > 1024.0f || (v != 0.0f && v < 9.5367431640625e-7f)) bad++;
    }
    atomicAdd(&cnt, bad);
    __syncthreads();
    if (threadIdx.x == 0) flag[0] = (cnt > 16) ? 1 : 0;
}

// ---- normalize any input buffer to bf16 (copy or fp32->bf16) --------------
__global__ __launch_bounds__(256) void conv_copy_k(const void* __restrict__ in,
                                                   u16* __restrict__ out, int n4,
                                                   const int* __restrict__ flag) {
    const int i = blockIdx.x * 256 + threadIdx.x;   // group of 4 elements
    if (i >= n4) return;
    if (flag[0]) {
        const float4 v = ((const float4*)in)[i];
        ushort4 o;
        o.x = f2bf(v.x); o.y = f2bf(v.y); o.z = f2bf(v.z); o.w = f2bf(v.w);
        ((ushort4*)out)[i] = o;
    } else {
        ((ushort4*)out)[i] = ((const ushort4*)in)[i];
    }
}

// ---- weight transpose with dtype normalization: in [R][C] -> out [C][R] ---
__global__ __launch_bounds__(256) void conv_transpose_k(const void* __restrict__ in,
                                                        u16* __restrict__ out,
                                                        int R, int C,
                                                        const int* __restrict__ flag) {
    __shared__ u16 t[32][33];
    const int isf = flag[0];
    const int c0 = blockIdx.x * 32, r0 = blockIdx.y * 32;
    const int tx = threadIdx.x & 31, ty = threadIdx.x >> 5;  // ty in 0..7
    for (int i = 0; i < 4; i++) {
        int r = ty + i * 8;
        size_t idx = (size_t)(r0 + r) * C + c0 + tx;
        t[r][tx] = isf ? f2bf(((const float*)in)[idx]) : ((const u16*)in)[idx];
    }
    __syncthreads();
    for (int i = 0; i < 4; i++) {
        int cr = ty + i * 8;
        out[(size_t)(c0 + cr) * R + r0 + tx] = t[tx][cr];
    }
}

// ---------------- QKV GEMM: X[8192,1024] @ Wt[3072,1024]^T + bias ----------
// epilogue: per-head affine on q/k (Q folded with softmax scale*log2e);
// Q,K -> [B,NH,T,HD];  V -> [B,NH,HD,T] (pre-transposed for attention)
__global__ __launch_bounds__(256) void qkv_gemm(
        const u16* __restrict__ X, const u16* __restrict__ Wt,
        const u16* __restrict__ pb,
        u16* __restrict__ Qb, u16* __restrict__ Kb, u16* __restrict__ Vb) {
    __shared__ __align__(16) u16 As[128 * 40];
    __shared__ __align__(16) u16 Bs[128 * 40];
    const int bm = blockIdx.y * 128, bn = blockIdx.x * 128;
    const int tid = threadIdx.x;
    const int lane = tid & 63, wave = tid >> 6;
    const int quad = lane >> 4, l16 = lane & 15;
    const int wm = (wave & 1) * 64, wn = (wave >> 1) * 64;

    floatx4 acc[4][4];
    for (int mi = 0; mi < 4; mi++)
        for (int ni = 0; ni < 4; ni++) acc[mi][ni] = 0.f;

    for (int k0 = 0; k0 < K_DIM; k0 += 32) {
        __syncthreads();
        for (int i = 0; i < 2; i++) {
            int cc = tid + i * 256;           // 512 chunks of 8 elements
            int r = cc >> 2, c8 = (cc & 3) * 8;
            *(float4*)&As[r * 40 + c8] =
                *(const float4*)&X[(size_t)(bm + r) * K_DIM + k0 + c8];
            *(float4*)&Bs[r * 40 + c8] =
                *(const float4*)&Wt[(size_t)(bn + r) * K_DIM + k0 + c8];
        }
        __syncthreads();
        short8 a[4], b[4];
        for (int mi = 0; mi < 4; mi++)
            a[mi] = *(const short8*)&As[(wm + mi * 16 + l16) * 40 + quad * 8];
        for (int ni = 0; ni < 4; ni++)
            b[ni] = *(const short8*)&Bs[(wn + ni * 16 + l16) * 40 + quad * 8];
        for (int mi = 0; mi < 4; mi++)
            for (int ni = 0; ni < 4; ni++)
                acc[mi][ni] = __builtin_amdgcn_mfma_f32_16x16x32_bf16(
                    a[mi], b[ni], acc[mi][ni], 0, 0, 0);
    }

    const int sec = bn >> 10;  // 0=q 1=k 2=v (128-tile never crosses 1024)
    const int bb = bm >> 11;   // batch index (constant per block)
    const int tbase = bm & 2047;
    for (int mi = 0; mi < 4; mi++) {
        for (int ni = 0; ni < 4; ni++) {
            const int col = bn + wn + ni * 16 + l16;
            const int cmod = col & 1023;
            const int h = cmod >> 6, d = cmod & 63;
            const float bv = bf2f(pb[PB_BQKV + col]);
            if (sec == 2) {
                // V: pack 4 consecutive t into one 8B store, [B,NH,HD,T]
                const int t0 = tbase + wm + mi * 16 + quad * 4;
                ushort4 pk;
                pk.x = f2bf(acc[mi][ni][0] + bv);
                pk.y = f2bf(acc[mi][ni][1] + bv);
                pk.z = f2bf(acc[mi][ni][2] + bv);
                pk.w = f2bf(acc[mi][ni][3] + bv);
                *(ushort4*)&Vb[(((size_t)(bb * NH_SZ + h)) * HD_SZ + d) * T_SZ + t0] = pk;
            } else {
                float sA, sB;
                if (sec == 0) {
                    sA = bf2f(pb[PB_QSC + h * 64 + d]) * QSCALE;
                    sB = bf2f(pb[PB_QBI + h * 64 + d]) * QSCALE;
                } else {
                    sA = bf2f(pb[PB_KSC + h * 64 + d]);
                    sB = bf2f(pb[PB_KBI + h * 64 + d]);
                }
                u16* dstbuf = (sec == 0) ? Qb : Kb;
                for (int r = 0; r < 4; r++) {
                    const int t = tbase + wm + mi * 16 + quad * 4 + r;
                    float v = (acc[mi][ni][r] + bv) * sA + sB;
                    dstbuf[(((size_t)(bb * NH_SZ + h)) * T_SZ + t) * HD_SZ + d] = f2bf(v);
                }
            }
        }
    }
}

// -------- Flash attention: block = (head, 128-row q tile), 8 waves ---------
// Q pre-scaled by 0.125*log2(e): scores are log2-domain, use exp2 directly.
__global__ __launch_bounds__(512) void attn_k(const u16* __restrict__ Qb,
                                              const u16* __restrict__ Kb,
                                              const u16* __restrict__ Vtg,
                                              u16* __restrict__ Y) {
    __shared__ __align__(16) u16 Qs[128 * 72];
    __shared__ __align__(16) u16 Ks[64 * 72];
    __shared__ __align__(16) u16 Vs[64 * 72];       // [d][key]
    __shared__ __align__(16) u16 Ps[8 * 16 * 68];   // per-wave [row][key], stride 68
    const int blk = blockIdx.x;
    const int head = blk >> 4;          // b*NH + h
    const int qt = 15 - (blk & 15);     // longest tiles dispatched first
    const int q0 = qt * 128;
    const int b = head >> 4, h = head & 15;
    const int tid = threadIdx.x, lane = tid & 63, w = tid >> 6;
    const int quad = lane >> 4, l16 = lane & 15;
    const size_t qk_off = (size_t)head * (T_SZ * HD_SZ);
    const size_t v_off = (size_t)head * (HD_SZ * T_SZ);

    for (int i = 0; i < 2; i++) {
        int cc = tid + i * 512;
        int r = cc >> 3, c8 = (cc & 7) * 8;
        *(float4*)&Qs[r * 72 + c8] =
            *(const float4*)&Qb[qk_off + (size_t)(q0 + r) * HD_SZ + c8];
    }

    floatx4 o[4];
    for (int ni = 0; ni < 4; ni++) o[ni] = 0.f;
    float mreg[4] = {-1e30f, -1e30f, -1e30f, -1e30f};
    float lreg[4] = {0.f, 0.f, 0.f, 0.f};
    const int rbase = q0 + w * 16;      // wave's first q row

    for (int k0 = 0; k0 < q0 + 128; k0 += 64) {
        __syncthreads();
        {
            int r = tid >> 3, c8 = (tid & 7) * 8;
            *(float4*)&Ks[r * 72 + c8] =
                *(const float4*)&Kb[qk_off + (size_t)(k0 + r) * HD_SZ + c8];
            *(float4*)&Vs[r * 72 + c8] =
                *(const float4*)&Vtg[v_off + (size_t)r * T_SZ + k0 + c8];
        }
        __syncthreads();
        if (k0 > rbase + 15) continue;  // fully masked for this wave

        floatx4 s[4];
        for (int ni = 0; ni < 4; ni++) s[ni] = 0.f;
        for (int kk = 0; kk < 64; kk += 32) {
            short8 a = *(const short8*)&Qs[(w * 16 + l16) * 72 + kk + quad * 8];
            for (int ni = 0; ni < 4; ni++) {
                short8 bfr = *(const short8*)&Ks[(ni * 16 + l16) * 72 + kk + quad * 8];
                s[ni] = __builtin_amdgcn_mfma_f32_16x16x32_bf16(a, bfr, s[ni], 0, 0, 0);
            }
        }

        if (k0 + 63 > rbase) {          // tile touches the diagonal
            for (int ni = 0; ni < 4; ni++)
                for (int r = 0; r < 4; r++) {
                    int gcol = k0 + ni * 16 + l16;
                    int grow = rbase + quad * 4 + r;
                    if (gcol > grow) s[ni][r] = -1e30f;
                }
        }

        for (int r = 0; r < 4; r++) {
            float rmax = fmaxf(fmaxf(s[0][r], s[1][r]), fmaxf(s[2][r], s[3][r]));
            for (int off = 1; off < 16; off <<= 1)
                rmax = fmaxf(rmax, __shfl_xor(rmax, off, 64));
            const float mold = mreg[r];
            const float mnew = fmaxf(mold, rmax);
            const float alpha = exp2f(mold - mnew);
            float rsum = 0.f;
            for (int ni = 0; ni < 4; ni++) {
                float pv = exp2f(s[ni][r] - mnew);
                s[ni][r] = pv;
                rsum += pv;
            }
            for (int off = 1; off < 16; off <<= 1)
                rsum += __shfl_xor(rsum, off, 64);
            mreg[r] = mnew;
            lreg[r] = lreg[r] * alpha + rsum;
            for (int ni = 0; ni < 4; ni++) o[ni][r] *= alpha;
        }

        // P round-trip through wave-private LDS (no barrier needed)
        for (int ni = 0; ni < 4; ni++)
            for (int r = 0; r < 4; r++)
                Ps[w * 1088 + (quad * 4 + r) * 68 + ni * 16 + l16] = f2bf(s[ni][r]);

        for (int kk = 0; kk < 64; kk += 32) {
            const u16* pp = &Ps[w * 1088 + l16 * 68 + kk + quad * 8];
            short4_t p0 = *(const short4_t*)pp;
            short4_t p1 = *(const short4_t*)(pp + 4);
            short8 a;
            for (int j = 0; j < 4; j++) { a[j] = p0[j]; a[4 + j] = p1[j]; }
            for (int ni = 0; ni < 4; ni++) {
                short8 bfr = *(const short8*)&Vs[(ni * 16 + l16) * 72 + kk + quad * 8];
                o[ni] = __builtin_amdgcn_mfma_f32_16x16x32_bf16(a, bfr, o[ni], 0, 0, 0);
            }
        }
    }

    // write y in [B,T,NH,HD] (= [B,T,C]) layout
    for (int r = 0; r < 4; r++) {
        const int row = rbase + quad * 4 + r;
        const float inv = 1.0f / lreg[r];
        for (int ni = 0; ni < 4; ni++) {
            Y[(((size_t)b * T_SZ + row) * NH_SZ + h) * HD_SZ + ni * 16 + l16] =
                f2bf(o[ni][r] * inv);
        }
    }
}

// ---------------- Proj GEMM: Y[8192,1024] @ Wt[1024,1024]^T + bias ---------
// output dtype branches on flag: fp32 (float*) or bf16 (u16*)
__global__ __launch_bounds__(256) void proj_gemm(const u16* __restrict__ Yin,
                                                 const u16* __restrict__ Wt,
                                                 const u16* __restrict__ pb,
                                                 void* __restrict__ out,
                                                 const int* __restrict__ flag) {
    __shared__ __align__(16) u16 As[128 * 40];
    __shared__ __align__(16) u16 Bs[128 * 40];
    const int isf = flag[0];
    const int bm = blockIdx.y * 128, bn = blockIdx.x * 128;
    const int tid = threadIdx.x;
    const int lane = tid & 63, wave = tid >> 6;
    const int quad = lane >> 4, l16 = lane & 15;
    const int wm = (wave & 1) * 64, wn = (wave >> 1) * 64;

    floatx4 acc[4][4];
    for (int mi = 0; mi < 4; mi++)
        for (int ni = 0; ni < 4; ni++) acc[mi][ni] = 0.f;

    for (int k0 = 0; k0 < K_DIM; k0 += 32) {
        __syncthreads();
        for (int i = 0; i < 2; i++) {
            int cc = tid + i * 256;
            int r = cc >> 2, c8 = (cc & 3) * 8;
            *(float4*)&As[r * 40 + c8] =
                *(const float4*)&Yin[(size_t)(bm + r) * K_DIM + k0 + c8];
            *(float4*)&Bs[r * 40 + c8] =
                *(const float4*)&Wt[(size_t)(bn + r) * K_DIM + k0 + c8];
        }
        __syncthreads();
        short8 a[4], b[4];
        for (int mi = 0; mi < 4; mi++)
            a[mi] = *(const short8*)&As[(wm + mi * 16 + l16) * 40 + quad * 8];
        for (int ni = 0; ni < 4; ni++)
            b[ni] = *(const short8*)&Bs[(wn + ni * 16 + l16) * 40 + quad * 8];
        for (int mi = 0; mi < 4; mi++)
            for (int ni = 0; ni < 4; ni++)
                acc[mi][ni] = __builtin_amdgcn_mfma_f32_16x16x32_bf16(
                    a[mi], b[ni], acc[mi][ni], 0, 0, 0);
    }

    for (int mi = 0; mi < 4; mi++) {
        for (int ni = 0; ni < 4; ni++) {
            const int col = bn + wn + ni * 16 + l16;
            const float bv = bf2f(pb[PB_BPROJ + col]);
            for (int r = 0; r < 4; r++) {
                const int row = bm + wm + mi * 16 + quad * 4 + r;
                const float v = acc[mi][ni][r] + bv;
                if (isf) ((float*)out)[(size_t)row * C_SZ + col] = v;
                else     ((u16*)out)[(size_t)row * C_SZ + col] = f2bf(v);
            }
        }
    }
}

extern "C" void kernel_launch(void* const* d_in, const int* in_sizes, int n_in,
                              void* d_out, int out_size, void* d_ws, size_t ws_size,
                              hipStream_t stream) {
    const void* x     = d_in[0];
    const void* Wqkv  = d_in[1];
    const void* bqkv  = d_in[2];
    const void* Wproj = d_in[3];
    const void* bproj = d_in[4];
    const void* qsc   = d_in[5];
    const void* qbi   = d_in[6];
    const void* ksc   = d_in[7];
    const void* kbi   = d_in[8];

    u16* ws = (u16*)d_ws;
    int* flag    = (int*)d_ws;
    u16* xb      = ws + OFF_XB;
    u16* Wt_qkv  = ws + OFF_WQT;
    u16* Wt_proj = ws + OFF_WPT;
    u16* pb      = ws + OFF_PB;
    u16* Qb      = ws + OFF_Q;
    u16* Kb      = ws + OFF_K;
    u16* Vb      = ws + OFF_V;     // [B,NH,HD,T]
    u16* Yb      = ws + OFF_Y;

    detect_k<<<1, 256, 0, stream>>>((const u16*)x, flag);

    conv_copy_k<<<8192, 256, 0, stream>>>(x, xb, 2097152, flag);
    conv_copy_k<<<3, 256, 0, stream>>>(bqkv, pb + PB_BQKV, 768, flag);
    conv_copy_k<<<1, 256, 0, stream>>>(bproj, pb + PB_BPROJ, 256, flag);
    conv_copy_k<<<1, 256, 0, stream>>>(qsc, pb + PB_QSC, 256, flag);
    conv_copy_k<<<1, 256, 0, stream>>>(qbi, pb + PB_QBI, 256, flag);
    conv_copy_k<<<1, 256, 0, stream>>>(ksc, pb + PB_KSC, 256, flag);
    conv_copy_k<<<1, 256, 0, stream>>>(kbi, pb + PB_KBI, 256, flag);
    conv_transpose_k<<<dim3(96, 32), 256, 0, stream>>>(Wqkv, Wt_qkv, 1024, 3072, flag);
    conv_transpose_k<<<dim3(32, 32), 256, 0, stream>>>(Wproj, Wt_proj, 1024, 1024, flag);

    qkv_gemm<<<dim3(24, 64), 256, 0, stream>>>(xb, Wt_qkv, pb, Qb, Kb, Vb);
    attn_k<<<dim3(1024), 512, 0, stream>>>(Qb, Kb, Vb, Yb);
    proj_gemm<<<dim3(8, 64), 256, 0, stream>>>(Yb, Wt_proj, pb, d_out, flag);
}

// Round 4
// 493.244 us; speedup vs baseline: 1.2149x; 1.0252x over previous
//
#include <hip/hip_runtime.h>
#include <hip/hip_bf16.h>

typedef unsigned short u16;
typedef __attribute__((ext_vector_type(8))) short short8;
typedef __attribute__((ext_vector_type(4))) short short4_t;
typedef __attribute__((ext_vector_type(4))) float floatx4;

#define B_SZ 4
#define T_SZ 2048
#define C_SZ 1024
#define NH_SZ 16
#define HD_SZ 64
#define M_TOT 8192      // B*T
#define K_DIM 1024      // C

// fold softmax 1/sqrt(64) and log2(e) into Q's affine: scores land in log2 domain
#define QSCALE 0.1803368801111204f   // 0.125 * 1.4426950408889634

// workspace layout (u16 element offsets from ws base; all 16B-aligned)
#define OFF_XB   ((size_t)16)
#define OFF_WQT  (OFF_XB + 8388608)
#define OFF_WPT  (OFF_WQT + 3145728)
#define OFF_PB   (OFF_WPT + 1048576)
#define OFF_Q    (OFF_PB + 8192)
#define OFF_K    (OFF_Q + 8388608)
#define OFF_V    (OFF_K + 8388608)
#define OFF_Y    (OFF_V + 8388608)
// params sub-layout inside PB (contiguous: sources in order)
#define PB_BQKV  0
#define PB_BPROJ 3072
#define PB_QSC   4096
#define PB_QBI   5120
#define PB_KSC   6144
#define PB_KBI   7168

__device__ __forceinline__ float bf2f(u16 u) {
    return __uint_as_float(((unsigned)u) << 16);
}
__device__ __forceinline__ u16 f2bf(float f) {
    unsigned x = __float_as_uint(f);
    unsigned r = (x + 0x7fffu + ((x >> 16) & 1u)) >> 16;
    return (u16)r;
}
// async global->LDS, 16B per lane; LDS dest = wave-uniform base + lane*16
__device__ __forceinline__ void gl_lds16(const u16* g, u16* l) {
    __builtin_amdgcn_global_load_lds(
        (const __attribute__((address_space(1))) void*)g,
        (__attribute__((address_space(3))) void*)l, 16, 0, 0);
}

// ---- dtype detector: fp32 reinterpreted as bf16 has wild exponents --------
__global__ __launch_bounds__(256) void detect_k(const u16* __restrict__ x,
                                                int* __restrict__ flag) {
    __shared__ int cnt;
    if (threadIdx.x == 0) cnt = 0;
    __syncthreads();
    int bad = 0;
    for (int i = threadIdx.x; i < 512; i += 256) {
        float v = fabsf(bf2f(x[i]));
        if (v > 1024.0f || (v != 0.0f && v < 9.5367431640625e-7f)) bad++;
    }
    atomicAdd(&cnt, bad);
    __syncthreads();
    if (threadIdx.x == 0) flag[0] = (cnt > 16) ? 1 : 0;
}

// ---- normalize x to bf16 (copy or fp32->bf16) -----------------------------
__global__ __launch_bounds__(256) void conv_copy_k(const void* __restrict__ in,
                                                   u16* __restrict__ out, int n4,
                                                   const int* __restrict__ flag) {
    const int i = blockIdx.x * 256 + threadIdx.x;   // group of 4 elements
    if (i >= n4) return;
    if (flag[0]) {
        const float4 v = ((const float4*)in)[i];
        ushort4 o;
        o.x = f2bf(v.x); o.y = f2bf(v.y); o.z = f2bf(v.z); o.w = f2bf(v.w);
        ((ushort4*)out)[i] = o;
    } else {
        ((ushort4*)out)[i] = ((const ushort4*)in)[i];
    }
}

// ---- all small param arrays -> contiguous pb buffer in one launch ---------
__global__ __launch_bounds__(256) void conv_params_k(
        const void* __restrict__ bqkv, const void* __restrict__ bproj,
        const void* __restrict__ qsc, const void* __restrict__ qbi,
        const void* __restrict__ ksc, const void* __restrict__ kbi,
        u16* __restrict__ pb, const int* __restrict__ flag) {
    const int i4 = blockIdx.x * 256 + threadIdx.x;  // 0..2047
    if (i4 >= 2048) return;
    const int e = i4 * 4;
    const void* src; int off;
    if (e < 3072)      { src = bqkv;  off = e; }
    else if (e < 4096) { src = bproj; off = e - 3072; }
    else if (e < 5120) { src = qsc;   off = e - 4096; }
    else if (e < 6144) { src = qbi;   off = e - 5120; }
    else if (e < 7168) { src = ksc;   off = e - 6144; }
    else               { src = kbi;   off = e - 7168; }
    ushort4 o;
    if (flag[0]) {
        const float4 v = *(const float4*)((const float*)src + off);
        o.x = f2bf(v.x); o.y = f2bf(v.y); o.z = f2bf(v.z); o.w = f2bf(v.w);
    } else {
        o = *(const ushort4*)((const u16*)src + off);
    }
    *(ushort4*)&pb[e] = o;
}

// ---- weight transpose with dtype normalization: in [R][C] -> out [C][R] ---
__global__ __launch_bounds__(256) void conv_transpose_k(const void* __restrict__ in,
                                                        u16* __restrict__ out,
                                                        int R, int C,
                                                        const int* __restrict__ flag) {
    __shared__ u16 t[32][33];
    const int isf = flag[0];
    const int c0 = blockIdx.x * 32, r0 = blockIdx.y * 32;
    const int tx = threadIdx.x & 31, ty = threadIdx.x >> 5;  // ty in 0..7
    for (int i = 0; i < 4; i++) {
        int r = ty + i * 8;
        size_t idx = (size_t)(r0 + r) * C + c0 + tx;
        t[r][tx] = isf ? f2bf(((const float*)in)[idx]) : ((const u16*)in)[idx];
    }
    __syncthreads();
    for (int i = 0; i < 4; i++) {
        int cr = ty + i * 8;
        out[(size_t)(c0 + cr) * R + r0 + tx] = t[tx][cr];
    }
}

// ---------------- QKV GEMM: X[8192,1024] @ Wt[3072,1024]^T + bias ----------
// m97-style staging: global_load_lds width 16, unpadded stride-32 LDS.
// epilogue: per-head affine on q/k (Q folded with softmax scale*log2e);
// Q,K -> [B,NH,T,HD];  V -> [B,NH,HD,T]
__global__ __launch_bounds__(256) void qkv_gemm(
        const u16* __restrict__ X, const u16* __restrict__ Wt,
        const u16* __restrict__ pb,
        u16* __restrict__ Qb, u16* __restrict__ Kb, u16* __restrict__ Vb) {
    __shared__ __align__(16) u16 As[128 * 32];
    __shared__ __align__(16) u16 Bs[128 * 32];
    const int bm = blockIdx.y * 128, bn = blockIdx.x * 128;
    const int tid = threadIdx.x;
    const int lane = tid & 63, wave = tid >> 6;
    const int quad = lane >> 4, l16 = lane & 15;
    const int wm = (wave & 1) * 64, wn = (wave >> 1) * 64;
    const int lrow = lane >> 2, lcol = (lane & 3) * 8;

    floatx4 acc[4][4];
    for (int mi = 0; mi < 4; mi++)
        for (int ni = 0; ni < 4; ni++) acc[mi][ni] = 0.f;

    for (int k0 = 0; k0 < K_DIM; k0 += 32) {
        __syncthreads();
        for (int j = 0; j < 2; j++) {
            gl_lds16(&X[(size_t)(bm + wave * 32 + j * 16 + lrow) * K_DIM + k0 + lcol],
                     &As[(wave * 32 + j * 16) * 32]);
            gl_lds16(&Wt[(size_t)(bn + wave * 32 + j * 16 + lrow) * K_DIM + k0 + lcol],
                     &Bs[(wave * 32 + j * 16) * 32]);
        }
        __syncthreads();
        short8 a[4], b[4];
        for (int mi = 0; mi < 4; mi++)
            a[mi] = *(const short8*)&As[(wm + mi * 16 + l16) * 32 + quad * 8];
        for (int ni = 0; ni < 4; ni++)
            b[ni] = *(const short8*)&Bs[(wn + ni * 16 + l16) * 32 + quad * 8];
        for (int mi = 0; mi < 4; mi++)
            for (int ni = 0; ni < 4; ni++)
                acc[mi][ni] = __builtin_amdgcn_mfma_f32_16x16x32_bf16(
                    a[mi], b[ni], acc[mi][ni], 0, 0, 0);
    }

    const int sec = bn >> 10;  // 0=q 1=k 2=v (128-tile never crosses 1024)
    const int bb = bm >> 11;   // batch index (constant per block)
    const int tbase = bm & 2047;
    for (int mi = 0; mi < 4; mi++) {
        for (int ni = 0; ni < 4; ni++) {
            const int col = bn + wn + ni * 16 + l16;
            const int cmod = col & 1023;
            const int h = cmod >> 6, d = cmod & 63;
            const float bv = bf2f(pb[PB_BQKV + col]);
            if (sec == 2) {
                const int t0 = tbase + wm + mi * 16 + quad * 4;
                ushort4 pk;
                pk.x = f2bf(acc[mi][ni][0] + bv);
                pk.y = f2bf(acc[mi][ni][1] + bv);
                pk.z = f2bf(acc[mi][ni][2] + bv);
                pk.w = f2bf(acc[mi][ni][3] + bv);
                *(ushort4*)&Vb[(((size_t)(bb * NH_SZ + h)) * HD_SZ + d) * T_SZ + t0] = pk;
            } else {
                float sA, sB;
                if (sec == 0) {
                    sA = bf2f(pb[PB_QSC + h * 64 + d]) * QSCALE;
                    sB = bf2f(pb[PB_QBI + h * 64 + d]) * QSCALE;
                } else {
                    sA = bf2f(pb[PB_KSC + h * 64 + d]);
                    sB = bf2f(pb[PB_KBI + h * 64 + d]);
                }
                u16* dstbuf = (sec == 0) ? Qb : Kb;
                for (int r = 0; r < 4; r++) {
                    const int t = tbase + wm + mi * 16 + quad * 4 + r;
                    float v = (acc[mi][ni][r] + bv) * sA + sB;
                    dstbuf[(((size_t)(bb * NH_SZ + h)) * T_SZ + t) * HD_SZ + d] = f2bf(v);
                }
            }
        }
    }
}

// -------- Flash attention: block = (head, 128-row q tile), 8 waves ---------
// Q pre-scaled by 0.125*log2(e); Q fragments held in registers (no Qs LDS
// buffer: LDS 35840 B -> 4 blocks/CU resident, grid = exactly 4 blocks/CU).
__global__ __launch_bounds__(512) void attn_k(const u16* __restrict__ Qb,
                                              const u16* __restrict__ Kb,
                                              const u16* __restrict__ Vtg,
                                              u16* __restrict__ Y) {
    __shared__ __align__(16) u16 Ks[64 * 72];
    __shared__ __align__(16) u16 Vs[64 * 72];       // [d][key]
    __shared__ __align__(16) u16 Ps[8 * 16 * 68];   // per-wave [row][key], stride 68
    const int blk = blockIdx.x;
    const int head = blk >> 4;          // b*NH + h
    const int qt = 15 - (blk & 15);     // longest tiles dispatched first
    const int q0 = qt * 128;
    const int b = head >> 4, h = head & 15;
    const int tid = threadIdx.x, lane = tid & 63, w = tid >> 6;
    const int quad = lane >> 4, l16 = lane & 15;
    const size_t qk_off = (size_t)head * (T_SZ * HD_SZ);
    const size_t v_off = (size_t)head * (HD_SZ * T_SZ);
    const int rbase = q0 + w * 16;      // wave's first q row

    // wave's Q block = exactly 2 A-fragments, straight from global
    const short8 aq0 = *(const short8*)&Qb[qk_off + (size_t)(rbase + l16) * HD_SZ + quad * 8];
    const short8 aq1 = *(const short8*)&Qb[qk_off + (size_t)(rbase + l16) * HD_SZ + 32 + quad * 8];

    floatx4 o[4];
    for (int ni = 0; ni < 4; ni++) o[ni] = 0.f;
    float mreg[4] = {-1e30f, -1e30f, -1e30f, -1e30f};
    float lreg[4] = {0.f, 0.f, 0.f, 0.f};

    for (int k0 = 0; k0 < q0 + 128; k0 += 64) {
        __syncthreads();
        {
            int r = tid >> 3, c8 = (tid & 7) * 8;
            *(float4*)&Ks[r * 72 + c8] =
                *(const float4*)&Kb[qk_off + (size_t)(k0 + r) * HD_SZ + c8];
            *(float4*)&Vs[r * 72 + c8] =
                *(const float4*)&Vtg[v_off + (size_t)r * T_SZ + k0 + c8];
        }
        __syncthreads();
        if (k0 > rbase + 15) continue;  // fully masked for this wave

        floatx4 s[4];
        for (int ni = 0; ni < 4; ni++) s[ni] = 0.f;
        for (int ni = 0; ni < 4; ni++)
            s[ni] = __builtin_amdgcn_mfma_f32_16x16x32_bf16(
                aq0, *(const short8*)&Ks[(ni * 16 + l16) * 72 + quad * 8], s[ni], 0, 0, 0);
        for (int ni = 0; ni < 4; ni++)
            s[ni] = __builtin_amdgcn_mfma_f32_16x16x32_bf16(
                aq1, *(const short8*)&Ks[(ni * 16 + l16) * 72 + 32 + quad * 8], s[ni], 0, 0, 0);

        if (k0 + 63 > rbase) {          // tile touches the diagonal
            for (int ni = 0; ni < 4; ni++)
                for (int r = 0; r < 4; r++) {
                    int gcol = k0 + ni * 16 + l16;
                    int grow = rbase + quad * 4 + r;
                    if (gcol > grow) s[ni][r] = -1e30f;
                }
        }

        for (int r = 0; r < 4; r++) {
            float rmax = fmaxf(fmaxf(s[0][r], s[1][r]), fmaxf(s[2][r], s[3][r]));
            for (int off = 1; off < 16; off <<= 1)
                rmax = fmaxf(rmax, __shfl_xor(rmax, off, 64));
            const float mold = mreg[r];
            const float mnew = fmaxf(mold, rmax);
            const float alpha = exp2f(mold - mnew);
            float rsum = 0.f;
            for (int ni = 0; ni < 4; ni++) {
                float pv = exp2f(s[ni][r] - mnew);
                s[ni][r] = pv;
                rsum += pv;
            }
            for (int off = 1; off < 16; off <<= 1)
                rsum += __shfl_xor(rsum, off, 64);
            mreg[r] = mnew;
            lreg[r] = lreg[r] * alpha + rsum;
            for (int ni = 0; ni < 4; ni++) o[ni][r] *= alpha;
        }

        // P round-trip through wave-private LDS (no barrier needed)
        for (int ni = 0; ni < 4; ni++)
            for (int r = 0; r < 4; r++)
                Ps[w * 1088 + (quad * 4 + r) * 68 + ni * 16 + l16] = f2bf(s[ni][r]);

        for (int kk = 0; kk < 64; kk += 32) {
            const u16* pp = &Ps[w * 1088 + l16 * 68 + kk + quad * 8];
            short4_t p0 = *(const short4_t*)pp;
            short4_t p1 = *(const short4_t*)(pp + 4);
            short8 a;
            for (int j = 0; j < 4; j++) { a[j] = p0[j]; a[4 + j] = p1[j]; }
            for (int ni = 0; ni < 4; ni++) {
                short8 bfr = *(const short8*)&Vs[(ni * 16 + l16) * 72 + kk + quad * 8];
                o[ni] = __builtin_amdgcn_mfma_f32_16x16x32_bf16(a, bfr, o[ni], 0, 0, 0);
            }
        }
    }

    // write y in [B,T,NH,HD] (= [B,T,C]) layout
    for (int r = 0; r < 4; r++) {
        const int row = rbase + quad * 4 + r;
        const float inv = 1.0f / lreg[r];
        for (int ni = 0; ni < 4; ni++) {
            Y[(((size_t)b * T_SZ + row) * NH_SZ + h) * HD_SZ + ni * 16 + l16] =
                f2bf(o[ni][r] * inv);
        }
    }
}

// ---------------- Proj GEMM: Y[8192,1024] @ Wt[1024,1024]^T + bias ---------
// m97-style staging; output dtype branches on flag
__global__ __launch_bounds__(256) void proj_gemm(const u16* __restrict__ Yin,
                                                 const u16* __restrict__ Wt,
                                                 const u16* __restrict__ pb,
                                                 void* __restrict__ out,
                                                 const int* __restrict__ flag) {
    __shared__ __align__(16) u16 As[128 * 32];
    __shared__ __align__(16) u16 Bs[128 * 32];
    const int isf = flag[0];
    const int bm = blockIdx.y * 128, bn = blockIdx.x * 128;
    const int tid = threadIdx.x;
    const int lane = tid & 63, wave = tid >> 6;
    const int quad = lane >> 4, l16 = lane & 15;
    const int wm = (wave & 1) * 64, wn = (wave >> 1) * 64;
    const int lrow = lane >> 2, lcol = (lane & 3) * 8;

    floatx4 acc[4][4];
    for (int mi = 0; mi < 4; mi++)
        for (int ni = 0; ni < 4; ni++) acc[mi][ni] = 0.f;

    for (int k0 = 0; k0 < K_DIM; k0 += 32) {
        __syncthreads();
        for (int j = 0; j < 2; j++) {
            gl_lds16(&Yin[(size_t)(bm + wave * 32 + j * 16 + lrow) * K_DIM + k0 + lcol],
                     &As[(wave * 32 + j * 16) * 32]);
            gl_lds16(&Wt[(size_t)(bn + wave * 32 + j * 16 + lrow) * K_DIM + k0 + lcol],
                     &Bs[(wave * 32 + j * 16) * 32]);
        }
        __syncthreads();
        short8 a[4], b[4];
        for (int mi = 0; mi < 4; mi++)
            a[mi] = *(const short8*)&As[(wm + mi * 16 + l16) * 32 + quad * 8];
        for (int ni = 0; ni < 4; ni++)
            b[ni] = *(const short8*)&Bs[(wn + ni * 16 + l16) * 32 + quad * 8];
        for (int mi = 0; mi < 4; mi++)
            for (int ni = 0; ni < 4; ni++)
                acc[mi][ni] = __builtin_amdgcn_mfma_f32_16x16x32_bf16(
                    a[mi], b[ni], acc[mi][ni], 0, 0, 0);
    }

    for (int mi = 0; mi < 4; mi++) {
        for (int ni = 0; ni < 4; ni++) {
            const int col = bn + wn + ni * 16 + l16;
            const float bv = bf2f(pb[PB_BPROJ + col]);
            for (int r = 0; r < 4; r++) {
                const int row = bm + wm + mi * 16 + quad * 4 + r;
                const float v = acc[mi][ni][r] + bv;
                if (isf) ((float*)out)[(size_t)row * C_SZ + col] = v;
                else     ((u16*)out)[(size_t)row * C_SZ + col] = f2bf(v);
            }
        }
    }
}

extern "C" void kernel_launch(void* const* d_in, const int* in_sizes, int n_in,
                              void* d_out, int out_size, void* d_ws, size_t ws_size,
                              hipStream_t stream) {
    const void* x     = d_in[0];
    const void* Wqkv  = d_in[1];
    const void* bqkv  = d_in[2];
    const void* Wproj = d_in[3];
    const void* bproj = d_in[4];
    const void* qsc   = d_in[5];
    const void* qbi   = d_in[6];
    const void* ksc   = d_in[7];
    const void* kbi   = d_in[8];

    u16* ws = (u16*)d_ws;
    int* flag    = (int*)d_ws;
    u16* xb      = ws + OFF_XB;
    u16* Wt_qkv  = ws + OFF_WQT;
    u16* Wt_proj = ws + OFF_WPT;
    u16* pb      = ws + OFF_PB;
    u16* Qb      = ws + OFF_Q;
    u16* Kb      = ws + OFF_K;
    u16* Vb      = ws + OFF_V;     // [B,NH,HD,T]
    u16* Yb      = ws + OFF_Y;

    detect_k<<<1, 256, 0, stream>>>((const u16*)x, flag);

    conv_copy_k<<<8192, 256, 0, stream>>>(x, xb, 2097152, flag);
    conv_params_k<<<8, 256, 0, stream>>>(bqkv, bproj, qsc, qbi, ksc, kbi, pb, flag);
    conv_transpose_k<<<dim3(96, 32), 256, 0, stream>>>(Wqkv, Wt_qkv, 1024, 3072, flag);
    conv_transpose_k<<<dim3(32, 32), 256, 0, stream>>>(Wproj, Wt_proj, 1024, 1024, flag);

    qkv_gemm<<<dim3(24, 64), 256, 0, stream>>>(xb, Wt_qkv, pb, Qb, Kb, Vb);
    attn_k<<<dim3(1024), 512, 0, stream>>>(Qb, Kb, Vb, Yb);
    proj_gemm<<<dim3(8, 64), 256, 0, stream>>>(Yb, Wt_proj, pb, d_out, flag);
}

// Round 5
// 367.765 us; speedup vs baseline: 1.6295x; 1.3412x over previous
//
#include <hip/hip_runtime.h>
#include <hip/hip_bf16.h>

typedef unsigned short u16;
typedef __attribute__((ext_vector_type(8))) short short8;
typedef __attribute__((ext_vector_type(4))) short short4_t;
typedef __attribute__((ext_vector_type(4))) float floatx4;

#define B_SZ 4
#define T_SZ 2048
#define C_SZ 1024
#define NH_SZ 16
#define HD_SZ 64
#define M_TOT 8192      // B*T
#define K_DIM 1024      // C

// fold softmax 1/sqrt(64) and log2(e) into Q's affine: scores land in log2 domain
#define QSCALE 0.1803368801111204f   // 0.125 * 1.4426950408889634

// workspace layout (u16 element offsets from ws base; all 16B-aligned)
#define OFF_XB   ((size_t)16)
#define OFF_WQT  (OFF_XB + 8388608)
#define OFF_WPT  (OFF_WQT + 3145728)
#define OFF_PB   (OFF_WPT + 1048576)
#define OFF_Q    (OFF_PB + 8192)
#define OFF_K    (OFF_Q + 8388608)
#define OFF_V    (OFF_K + 8388608)
#define OFF_Y    (OFF_V + 8388608)
// params sub-layout inside PB (contiguous: sources in order)
#define PB_BQKV  0
#define PB_BPROJ 3072
#define PB_QSC   4096
#define PB_QBI   5120
#define PB_KSC   6144
#define PB_KBI   7168

__device__ __forceinline__ float bf2f(u16 u) {
    return __uint_as_float(((unsigned)u) << 16);
}
__device__ __forceinline__ u16 f2bf(float f) {
    unsigned x = __float_as_uint(f);
    unsigned r = (x + 0x7fffu + ((x >> 16) & 1u)) >> 16;
    return (u16)r;
}
// async global->LDS, 16B per lane; LDS dest = wave-uniform base + lane*16
__device__ __forceinline__ void gl_lds16(const u16* g, u16* l) {
    __builtin_amdgcn_global_load_lds(
        (const __attribute__((address_space(1))) void*)g,
        (__attribute__((address_space(3))) void*)l, 16, 0, 0);
}

// ---- dtype detector: fp32 reinterpreted as bf16 has wild exponents --------
__global__ __launch_bounds__(256) void detect_k(const u16* __restrict__ x,
                                                int* __restrict__ flag) {
    __shared__ int cnt;
    if (threadIdx.x == 0) cnt = 0;
    __syncthreads();
    int bad = 0;
    for (int i = threadIdx.x; i < 512; i += 256) {
        float v = fabsf(bf2f(x[i]));
        if (v > 1024.0f || (v != 0.0f && v < 9.5367431640625e-7f)) bad++;
    }
    atomicAdd(&cnt, bad);
    __syncthreads();
    if (threadIdx.x == 0) flag[0] = (cnt > 16) ? 1 : 0;
}

// ---- normalize x to bf16 (copy or fp32->bf16) -----------------------------
__global__ __launch_bounds__(256) void conv_copy_k(const void* __restrict__ in,
                                                   u16* __restrict__ out, int n4,
                                                   const int* __restrict__ flag) {
    const int i = blockIdx.x * 256 + threadIdx.x;   // group of 4 elements
    if (i >= n4) return;
    if (flag[0]) {
        const float4 v = ((const float4*)in)[i];
        ushort4 o;
        o.x = f2bf(v.x); o.y = f2bf(v.y); o.z = f2bf(v.z); o.w = f2bf(v.w);
        ((ushort4*)out)[i] = o;
    } else {
        ((ushort4*)out)[i] = ((const ushort4*)in)[i];
    }
}

// ---- all small param arrays -> contiguous pb buffer in one launch ---------
__global__ __launch_bounds__(256) void conv_params_k(
        const void* __restrict__ bqkv, const void* __restrict__ bproj,
        const void* __restrict__ qsc, const void* __restrict__ qbi,
        const void* __restrict__ ksc, const void* __restrict__ kbi,
        u16* __restrict__ pb, const int* __restrict__ flag) {
    const int i4 = blockIdx.x * 256 + threadIdx.x;  // 0..2047
    if (i4 >= 2048) return;
    const int e = i4 * 4;
    const void* src; int off;
    if (e < 3072)      { src = bqkv;  off = e; }
    else if (e < 4096) { src = bproj; off = e - 3072; }
    else if (e < 5120) { src = qsc;   off = e - 4096; }
    else if (e < 6144) { src = qbi;   off = e - 5120; }
    else if (e < 7168) { src = ksc;   off = e - 6144; }
    else               { src = kbi;   off = e - 7168; }
    ushort4 o;
    if (flag[0]) {
        const float4 v = *(const float4*)((const float*)src + off);
        o.x = f2bf(v.x); o.y = f2bf(v.y); o.z = f2bf(v.z); o.w = f2bf(v.w);
    } else {
        o = *(const ushort4*)((const u16*)src + off);
    }
    *(ushort4*)&pb[e] = o;
}

// ---- weight transpose with dtype normalization: in [R][C] -> out [C][R] ---
__global__ __launch_bounds__(256) void conv_transpose_k(const void* __restrict__ in,
                                                        u16* __restrict__ out,
                                                        int R, int C,
                                                        const int* __restrict__ flag) {
    __shared__ u16 t[32][33];
    const int isf = flag[0];
    const int c0 = blockIdx.x * 32, r0 = blockIdx.y * 32;
    const int tx = threadIdx.x & 31, ty = threadIdx.x >> 5;  // ty in 0..7
    for (int i = 0; i < 4; i++) {
        int r = ty + i * 8;
        size_t idx = (size_t)(r0 + r) * C + c0 + tx;
        t[r][tx] = isf ? f2bf(((const float*)in)[idx]) : ((const u16*)in)[idx];
    }
    __syncthreads();
    for (int i = 0; i < 4; i++) {
        int cr = ty + i * 8;
        out[(size_t)(c0 + cr) * R + r0 + tx] = t[tx][cr];
    }
}

// ---------------- QKV GEMM: X[8192,1024] @ Wt[3072,1024]^T + bias ----------
// m97-config: BK=64, global_load_lds width 16, unpadded stride-64 LDS.
// epilogue: per-head affine on q/k (Q folded with softmax scale*log2e);
// Q,K -> [B,NH,T,HD];  V -> [B,NH,HD,T]
__global__ __launch_bounds__(256) void qkv_gemm(
        const u16* __restrict__ X, const u16* __restrict__ Wt,
        const u16* __restrict__ pb,
        u16* __restrict__ Qb, u16* __restrict__ Kb, u16* __restrict__ Vb) {
    __shared__ __align__(16) u16 As[128 * 64];
    __shared__ __align__(16) u16 Bs[128 * 64];
    const int bm = blockIdx.y * 128, bn = blockIdx.x * 128;
    const int tid = threadIdx.x;
    const int lane = tid & 63, wave = tid >> 6;
    const int quad = lane >> 4, l16 = lane & 15;
    const int wm = (wave & 1) * 64, wn = (wave >> 1) * 64;
    const int lrow = lane >> 3, lcol = (lane & 7) * 8;   // 8 rows x 64 cols per inst

    floatx4 acc[4][4];
    for (int mi = 0; mi < 4; mi++)
        for (int ni = 0; ni < 4; ni++) acc[mi][ni] = 0.f;

    for (int k0 = 0; k0 < K_DIM; k0 += 64) {
        __syncthreads();
        for (int j = 0; j < 4; j++) {
            const int rb = wave * 32 + j * 8;
            gl_lds16(&X[(size_t)(bm + rb + lrow) * K_DIM + k0 + lcol], &As[rb * 64]);
            gl_lds16(&Wt[(size_t)(bn + rb + lrow) * K_DIM + k0 + lcol], &Bs[rb * 64]);
        }
        __syncthreads();
        for (int kk = 0; kk < 64; kk += 32) {
            short8 a[4], b[4];
            for (int mi = 0; mi < 4; mi++)
                a[mi] = *(const short8*)&As[(wm + mi * 16 + l16) * 64 + kk + quad * 8];
            for (int ni = 0; ni < 4; ni++)
                b[ni] = *(const short8*)&Bs[(wn + ni * 16 + l16) * 64 + kk + quad * 8];
            for (int mi = 0; mi < 4; mi++)
                for (int ni = 0; ni < 4; ni++)
                    acc[mi][ni] = __builtin_amdgcn_mfma_f32_16x16x32_bf16(
                        a[mi], b[ni], acc[mi][ni], 0, 0, 0);
        }
    }

    const int sec = bn >> 10;  // 0=q 1=k 2=v (128-tile never crosses 1024)
    const int bb = bm >> 11;   // batch index (constant per block)
    const int tbase = bm & 2047;
    for (int mi = 0; mi < 4; mi++) {
        for (int ni = 0; ni < 4; ni++) {
            const int col = bn + wn + ni * 16 + l16;
            const int cmod = col & 1023;
            const int h = cmod >> 6, d = cmod & 63;
            const float bv = bf2f(pb[PB_BQKV + col]);
            if (sec == 2) {
                const int t0 = tbase + wm + mi * 16 + quad * 4;
                ushort4 pk;
                pk.x = f2bf(acc[mi][ni][0] + bv);
                pk.y = f2bf(acc[mi][ni][1] + bv);
                pk.z = f2bf(acc[mi][ni][2] + bv);
                pk.w = f2bf(acc[mi][ni][3] + bv);
                *(ushort4*)&Vb[(((size_t)(bb * NH_SZ + h)) * HD_SZ + d) * T_SZ + t0] = pk;
            } else {
                float sA, sB;
                if (sec == 0) {
                    sA = bf2f(pb[PB_QSC + h * 64 + d]) * QSCALE;
                    sB = bf2f(pb[PB_QBI + h * 64 + d]) * QSCALE;
                } else {
                    sA = bf2f(pb[PB_KSC + h * 64 + d]);
                    sB = bf2f(pb[PB_KBI + h * 64 + d]);
                }
                u16* dstbuf = (sec == 0) ? Qb : Kb;
                for (int r = 0; r < 4; r++) {
                    const int t = tbase + wm + mi * 16 + quad * 4 + r;
                    float v = (acc[mi][ni][r] + bv) * sA + sB;
                    dstbuf[(((size_t)(bb * NH_SZ + h)) * T_SZ + t) * HD_SZ + d] = f2bf(v);
                }
            }
        }
    }
}

// -------- Flash attention: block = (head, diagonal tile-pair), 8 waves -----
// Causal pairing: block p processes q-tiles (15-p) then (p) sequentially.
// Total k-iterations = 2(16-p) + 2(p+1) = 34 for EVERY block -> uniform
// makespan, no dependence on dispatch order. 512 blocks = 2/CU.
__global__ __launch_bounds__(512) void attn_k(const u16* __restrict__ Qb,
                                              const u16* __restrict__ Kb,
                                              const u16* __restrict__ Vtg,
                                              u16* __restrict__ Y) {
    __shared__ __align__(16) u16 Ks[64 * 72];
    __shared__ __align__(16) u16 Vs[64 * 72];       // [d][key]
    __shared__ __align__(16) u16 Ps[8 * 16 * 68];   // per-wave [row][key], stride 68
    const int blk = blockIdx.x;
    const int head = blk & 63;          // b*NH + h
    const int p = blk >> 6;             // pair index 0..7
    const int b = head >> 4, h = head & 15;
    const int tid = threadIdx.x, lane = tid & 63, w = tid >> 6;
    const int quad = lane >> 4, l16 = lane & 15;
    const size_t qk_off = (size_t)head * (T_SZ * HD_SZ);
    const size_t v_off = (size_t)head * (HD_SZ * T_SZ);

    for (int tile = 0; tile < 2; tile++) {
        const int qt = tile ? p : (15 - p);
        const int q0 = qt * 128;
        const int rbase = q0 + w * 16;  // wave's first q row

        // wave's Q block = exactly 2 A-fragments, straight from global
        const short8 aq0 = *(const short8*)&Qb[qk_off + (size_t)(rbase + l16) * HD_SZ + quad * 8];
        const short8 aq1 = *(const short8*)&Qb[qk_off + (size_t)(rbase + l16) * HD_SZ + 32 + quad * 8];

        floatx4 o[4];
        for (int ni = 0; ni < 4; ni++) o[ni] = 0.f;
        float mreg[4] = {-1e30f, -1e30f, -1e30f, -1e30f};
        float lreg[4] = {0.f, 0.f, 0.f, 0.f};

        for (int k0 = 0; k0 < q0 + 128; k0 += 64) {
            __syncthreads();
            {
                int r = tid >> 3, c8 = (tid & 7) * 8;
                *(float4*)&Ks[r * 72 + c8] =
                    *(const float4*)&Kb[qk_off + (size_t)(k0 + r) * HD_SZ + c8];
                *(float4*)&Vs[r * 72 + c8] =
                    *(const float4*)&Vtg[v_off + (size_t)r * T_SZ + k0 + c8];
            }
            __syncthreads();
            if (k0 > rbase + 15) continue;  // fully masked for this wave

            floatx4 s[4];
            for (int ni = 0; ni < 4; ni++) s[ni] = 0.f;
            for (int ni = 0; ni < 4; ni++)
                s[ni] = __builtin_amdgcn_mfma_f32_16x16x32_bf16(
                    aq0, *(const short8*)&Ks[(ni * 16 + l16) * 72 + quad * 8], s[ni], 0, 0, 0);
            for (int ni = 0; ni < 4; ni++)
                s[ni] = __builtin_amdgcn_mfma_f32_16x16x32_bf16(
                    aq1, *(const short8*)&Ks[(ni * 16 + l16) * 72 + 32 + quad * 8], s[ni], 0, 0, 0);

            if (k0 + 63 > rbase) {          // tile touches the diagonal
                for (int ni = 0; ni < 4; ni++)
                    for (int r = 0; r < 4; r++) {
                        int gcol = k0 + ni * 16 + l16;
                        int grow = rbase + quad * 4 + r;
                        if (gcol > grow) s[ni][r] = -1e30f;
                    }
            }

            for (int r = 0; r < 4; r++) {
                float rmax = fmaxf(fmaxf(s[0][r], s[1][r]), fmaxf(s[2][r], s[3][r]));
                for (int off = 1; off < 16; off <<= 1)
                    rmax = fmaxf(rmax, __shfl_xor(rmax, off, 64));
                const float mold = mreg[r];
                const float mnew = fmaxf(mold, rmax);
                const float alpha = exp2f(mold - mnew);
                float rsum = 0.f;
                for (int ni = 0; ni < 4; ni++) {
                    float pv = exp2f(s[ni][r] - mnew);
                    s[ni][r] = pv;
                    rsum += pv;
                }
                for (int off = 1; off < 16; off <<= 1)
                    rsum += __shfl_xor(rsum, off, 64);
                mreg[r] = mnew;
                lreg[r] = lreg[r] * alpha + rsum;
                for (int ni = 0; ni < 4; ni++) o[ni][r] *= alpha;
            }

            // P round-trip through wave-private LDS (no barrier needed)
            for (int ni = 0; ni < 4; ni++)
                for (int r = 0; r < 4; r++)
                    Ps[w * 1088 + (quad * 4 + r) * 68 + ni * 16 + l16] = f2bf(s[ni][r]);

            for (int kk = 0; kk < 64; kk += 32) {
                const u16* pp = &Ps[w * 1088 + l16 * 68 + kk + quad * 8];
                short4_t p0 = *(const short4_t*)pp;
                short4_t p1 = *(const short4_t*)(pp + 4);
                short8 a;
                for (int j = 0; j < 4; j++) { a[j] = p0[j]; a[4 + j] = p1[j]; }
                for (int ni = 0; ni < 4; ni++) {
                    short8 bfr = *(const short8*)&Vs[(ni * 16 + l16) * 72 + kk + quad * 8];
                    o[ni] = __builtin_amdgcn_mfma_f32_16x16x32_bf16(a, bfr, o[ni], 0, 0, 0);
                }
            }
        }

        // write y in [B,T,NH,HD] (= [B,T,C]) layout
        for (int r = 0; r < 4; r++) {
            const int row = rbase + quad * 4 + r;
            const float inv = 1.0f / lreg[r];
            for (int ni = 0; ni < 4; ni++) {
                Y[(((size_t)b * T_SZ + row) * NH_SZ + h) * HD_SZ + ni * 16 + l16] =
                    f2bf(o[ni][r] * inv);
            }
        }
    }
}

// ---------------- Proj GEMM: Y[8192,1024] @ Wt[1024,1024]^T + bias ---------
// m97-config BK=64 staging; output dtype branches on flag
__global__ __launch_bounds__(256) void proj_gemm(const u16* __restrict__ Yin,
                                                 const u16* __restrict__ Wt,
                                                 const u16* __restrict__ pb,
                                                 void* __restrict__ out,
                                                 const int* __restrict__ flag) {
    __shared__ __align__(16) u16 As[128 * 64];
    __shared__ __align__(16) u16 Bs[128 * 64];
    const int isf = flag[0];
    const int bm = blockIdx.y * 128, bn = blockIdx.x * 128;
    const int tid = threadIdx.x;
    const int lane = tid & 63, wave = tid >> 6;
    const int quad = lane >> 4, l16 = lane & 15;
    const int wm = (wave & 1) * 64, wn = (wave >> 1) * 64;
    const int lrow = lane >> 3, lcol = (lane & 7) * 8;

    floatx4 acc[4][4];
    for (int mi = 0; mi < 4; mi++)
        for (int ni = 0; ni < 4; ni++) acc[mi][ni] = 0.f;

    for (int k0 = 0; k0 < K_DIM; k0 += 64) {
        __syncthreads();
        for (int j = 0; j < 4; j++) {
            const int rb = wave * 32 + j * 8;
            gl_lds16(&Yin[(size_t)(bm + rb + lrow) * K_DIM + k0 + lcol], &As[rb * 64]);
            gl_lds16(&Wt[(size_t)(bn + rb + lrow) * K_DIM + k0 + lcol], &Bs[rb * 64]);
        }
        __syncthreads();
        for (int kk = 0; kk < 64; kk += 32) {
            short8 a[4], b[4];
            for (int mi = 0; mi < 4; mi++)
                a[mi] = *(const short8*)&As[(wm + mi * 16 + l16) * 64 + kk + quad * 8];
            for (int ni = 0; ni < 4; ni++)
                b[ni] = *(const short8*)&Bs[(wn + ni * 16 + l16) * 64 + kk + quad * 8];
            for (int mi = 0; mi < 4; mi++)
                for (int ni = 0; ni < 4; ni++)
                    acc[mi][ni] = __builtin_amdgcn_mfma_f32_16x16x32_bf16(
                        a[mi], b[ni], acc[mi][ni], 0, 0, 0);
        }
    }

    for (int mi = 0; mi < 4; mi++) {
        for (int ni = 0; ni < 4; ni++) {
            const int col = bn + wn + ni * 16 + l16;
            const float bv = bf2f(pb[PB_BPROJ + col]);
            for (int r = 0; r < 4; r++) {
                const int row = bm + wm + mi * 16 + quad * 4 + r;
                const float v = acc[mi][ni][r] + bv;
                if (isf) ((float*)out)[(size_t)row * C_SZ + col] = v;
                else     ((u16*)out)[(size_t)row * C_SZ + col] = f2bf(v);
            }
        }
    }
}

extern "C" void kernel_launch(void* const* d_in, const int* in_sizes, int n_in,
                              void* d_out, int out_size, void* d_ws, size_t ws_size,
                              hipStream_t stream) {
    const void* x     = d_in[0];
    const void* Wqkv  = d_in[1];
    const void* bqkv  = d_in[2];
    const void* Wproj = d_in[3];
    const void* bproj = d_in[4];
    const void* qsc   = d_in[5];
    const void* qbi   = d_in[6];
    const void* ksc   = d_in[7];
    const void* kbi   = d_in[8];

    u16* ws = (u16*)d_ws;
    int* flag    = (int*)d_ws;
    u16* xb      = ws + OFF_XB;
    u16* Wt_qkv  = ws + OFF_WQT;
    u16* Wt_proj = ws + OFF_WPT;
    u16* pb      = ws + OFF_PB;
    u16* Qb      = ws + OFF_Q;
    u16* Kb      = ws + OFF_K;
    u16* Vb      = ws + OFF_V;     // [B,NH,HD,T]
    u16* Yb      = ws + OFF_Y;

    detect_k<<<1, 256, 0, stream>>>((const u16*)x, flag);

    conv_copy_k<<<8192, 256, 0, stream>>>(x, xb, 2097152, flag);
    conv_params_k<<<8, 256, 0, stream>>>(bqkv, bproj, qsc, qbi, ksc, kbi, pb, flag);
    conv_transpose_k<<<dim3(96, 32), 256, 0, stream>>>(Wqkv, Wt_qkv, 1024, 3072, flag);
    conv_transpose_k<<<dim3(32, 32), 256, 0, stream>>>(Wproj, Wt_proj, 1024, 1024, flag);

    qkv_gemm<<<dim3(24, 64), 256, 0, stream>>>(xb, Wt_qkv, pb, Qb, Kb, Vb);
    attn_k<<<dim3(512), 512, 0, stream>>>(Qb, Kb, Vb, Yb);
    proj_gemm<<<dim3(8, 64), 256, 0, stream>>>(Yb, Wt_proj, pb, d_out, flag);
}

// Round 6
// 331.869 us; speedup vs baseline: 1.8057x; 1.1082x over previous
//
#include <hip/hip_runtime.h>
#include <hip/hip_bf16.h>

typedef unsigned short u16;
typedef __attribute__((ext_vector_type(8))) short short8;
typedef __attribute__((ext_vector_type(4))) float floatx4;

#define B_SZ 4
#define T_SZ 2048
#define C_SZ 1024
#define NH_SZ 16
#define HD_SZ 64
#define M_TOT 8192      // B*T
#define K_DIM 1024      // C

// fold softmax 1/sqrt(64) and log2(e) into Q's affine: scores land in log2 domain
#define QSCALE 0.1803368801111204f   // 0.125 * 1.4426950408889634

// workspace layout (u16 element offsets from ws base; all 16B-aligned)
#define OFF_XB   ((size_t)16)
#define OFF_WQT  (OFF_XB + 8388608)
#define OFF_WPT  (OFF_WQT + 3145728)
#define OFF_PB   (OFF_WPT + 1048576)
#define OFF_Q    (OFF_PB + 8192)
#define OFF_K    (OFF_Q + 8388608)
#define OFF_V    (OFF_K + 8388608)
#define OFF_Y    (OFF_V + 8388608)
// params sub-layout inside PB (contiguous: sources in order)
#define PB_BQKV  0
#define PB_BPROJ 3072
#define PB_QSC   4096
#define PB_QBI   5120
#define PB_KSC   6144
#define PB_KBI   7168

__device__ __forceinline__ float bf2f(u16 u) {
    return __uint_as_float(((unsigned)u) << 16);
}
__device__ __forceinline__ u16 f2bf(float f) {
    unsigned x = __float_as_uint(f);
    unsigned r = (x + 0x7fffu + ((x >> 16) & 1u)) >> 16;
    return (u16)r;
}
// async global->LDS, 16B per lane; LDS dest = wave-uniform base + lane*16
__device__ __forceinline__ void gl_lds16(const u16* g, u16* l) {
    __builtin_amdgcn_global_load_lds(
        (const __attribute__((address_space(1))) void*)g,
        (__attribute__((address_space(3))) void*)l, 16, 0, 0);
}

// ---- dtype detector: fp32 reinterpreted as bf16 has wild exponents --------
__global__ __launch_bounds__(256) void detect_k(const u16* __restrict__ x,
                                                int* __restrict__ flag) {
    __shared__ int cnt;
    if (threadIdx.x == 0) cnt = 0;
    __syncthreads();
    int bad = 0;
    for (int i = threadIdx.x; i < 512; i += 256) {
        float v = fabsf(bf2f(x[i]));
        if (v > 1024.0f || (v != 0.0f && v < 9.5367431640625e-7f)) bad++;
    }
    atomicAdd(&cnt, bad);
    __syncthreads();
    if (threadIdx.x == 0) flag[0] = (cnt > 16) ? 1 : 0;
}

// ---- normalize x to bf16 (copy or fp32->bf16) -----------------------------
__global__ __launch_bounds__(256) void conv_copy_k(const void* __restrict__ in,
                                                   u16* __restrict__ out, int n4,
                                                   const int* __restrict__ flag) {
    const int i = blockIdx.x * 256 + threadIdx.x;   // group of 4 elements
    if (i >= n4) return;
    if (flag[0]) {
        const float4 v = ((const float4*)in)[i];
        ushort4 o;
        o.x = f2bf(v.x); o.y = f2bf(v.y); o.z = f2bf(v.z); o.w = f2bf(v.w);
        ((ushort4*)out)[i] = o;
    } else {
        ((ushort4*)out)[i] = ((const ushort4*)in)[i];
    }
}

// ---- all small param arrays -> contiguous pb buffer in one launch ---------
__global__ __launch_bounds__(256) void conv_params_k(
        const void* __restrict__ bqkv, const void* __restrict__ bproj,
        const void* __restrict__ qsc, const void* __restrict__ qbi,
        const void* __restrict__ ksc, const void* __restrict__ kbi,
        u16* __restrict__ pb, const int* __restrict__ flag) {
    const int i4 = blockIdx.x * 256 + threadIdx.x;  // 0..2047
    if (i4 >= 2048) return;
    const int e = i4 * 4;
    const void* src; int off;
    if (e < 3072)      { src = bqkv;  off = e; }
    else if (e < 4096) { src = bproj; off = e - 3072; }
    else if (e < 5120) { src = qsc;   off = e - 4096; }
    else if (e < 6144) { src = qbi;   off = e - 5120; }
    else if (e < 7168) { src = ksc;   off = e - 6144; }
    else               { src = kbi;   off = e - 7168; }
    ushort4 o;
    if (flag[0]) {
        const float4 v = *(const float4*)((const float*)src + off);
        o.x = f2bf(v.x); o.y = f2bf(v.y); o.z = f2bf(v.z); o.w = f2bf(v.w);
    } else {
        o = *(const ushort4*)((const u16*)src + off);
    }
    *(ushort4*)&pb[e] = o;
}

// ---- weight transpose with dtype normalization: in [R][C] -> out [C][R] ---
__global__ __launch_bounds__(256) void conv_transpose_k(const void* __restrict__ in,
                                                        u16* __restrict__ out,
                                                        int R, int C,
                                                        const int* __restrict__ flag) {
    __shared__ u16 t[32][33];
    const int isf = flag[0];
    const int c0 = blockIdx.x * 32, r0 = blockIdx.y * 32;
    const int tx = threadIdx.x & 31, ty = threadIdx.x >> 5;  // ty in 0..7
    for (int i = 0; i < 4; i++) {
        int r = ty + i * 8;
        size_t idx = (size_t)(r0 + r) * C + c0 + tx;
        t[r][tx] = isf ? f2bf(((const float*)in)[idx]) : ((const u16*)in)[idx];
    }
    __syncthreads();
    for (int i = 0; i < 4; i++) {
        int cr = ty + i * 8;
        out[(size_t)(c0 + cr) * R + r0 + tx] = t[tx][cr];
    }
}

// ---------------- QKV GEMM: X[8192,1024] @ Wt[3072,1024]^T + bias ----------
// m97-config: BK=64, global_load_lds width 16, unpadded stride-64 LDS.
// epilogue: per-head affine on q/k (Q folded with softmax scale*log2e);
// Q,K -> [B,NH,T,HD];  V -> [B,NH,HD,T]
__global__ __launch_bounds__(256) void qkv_gemm(
        const u16* __restrict__ X, const u16* __restrict__ Wt,
        const u16* __restrict__ pb,
        u16* __restrict__ Qb, u16* __restrict__ Kb, u16* __restrict__ Vb) {
    __shared__ __align__(16) u16 As[128 * 64];
    __shared__ __align__(16) u16 Bs[128 * 64];
    const int bm = blockIdx.y * 128, bn = blockIdx.x * 128;
    const int tid = threadIdx.x;
    const int lane = tid & 63, wave = tid >> 6;
    const int quad = lane >> 4, l16 = lane & 15;
    const int wm = (wave & 1) * 64, wn = (wave >> 1) * 64;
    const int lrow = lane >> 3, lcol = (lane & 7) * 8;   // 8 rows x 64 cols per inst

    floatx4 acc[4][4];
    for (int mi = 0; mi < 4; mi++)
        for (int ni = 0; ni < 4; ni++) acc[mi][ni] = 0.f;

    for (int k0 = 0; k0 < K_DIM; k0 += 64) {
        __syncthreads();
        for (int j = 0; j < 4; j++) {
            const int rb = wave * 32 + j * 8;
            gl_lds16(&X[(size_t)(bm + rb + lrow) * K_DIM + k0 + lcol], &As[rb * 64]);
            gl_lds16(&Wt[(size_t)(bn + rb + lrow) * K_DIM + k0 + lcol], &Bs[rb * 64]);
        }
        __syncthreads();
        for (int kk = 0; kk < 64; kk += 32) {
            short8 a[4], b[4];
            for (int mi = 0; mi < 4; mi++)
                a[mi] = *(const short8*)&As[(wm + mi * 16 + l16) * 64 + kk + quad * 8];
            for (int ni = 0; ni < 4; ni++)
                b[ni] = *(const short8*)&Bs[(wn + ni * 16 + l16) * 64 + kk + quad * 8];
            for (int mi = 0; mi < 4; mi++)
                for (int ni = 0; ni < 4; ni++)
                    acc[mi][ni] = __builtin_amdgcn_mfma_f32_16x16x32_bf16(
                        a[mi], b[ni], acc[mi][ni], 0, 0, 0);
        }
    }

    const int sec = bn >> 10;  // 0=q 1=k 2=v (128-tile never crosses 1024)
    const int bb = bm >> 11;   // batch index (constant per block)
    const int tbase = bm & 2047;
    for (int mi = 0; mi < 4; mi++) {
        for (int ni = 0; ni < 4; ni++) {
            const int col = bn + wn + ni * 16 + l16;
            const int cmod = col & 1023;
            const int h = cmod >> 6, d = cmod & 63;
            const float bv = bf2f(pb[PB_BQKV + col]);
            if (sec == 2) {
                const int t0 = tbase + wm + mi * 16 + quad * 4;
                ushort4 pk;
                pk.x = f2bf(acc[mi][ni][0] + bv);
                pk.y = f2bf(acc[mi][ni][1] + bv);
                pk.z = f2bf(acc[mi][ni][2] + bv);
                pk.w = f2bf(acc[mi][ni][3] + bv);
                *(ushort4*)&Vb[(((size_t)(bb * NH_SZ + h)) * HD_SZ + d) * T_SZ + t0] = pk;
            } else {
                float sA, sB;
                if (sec == 0) {
                    sA = bf2f(pb[PB_QSC + h * 64 + d]) * QSCALE;
                    sB = bf2f(pb[PB_QBI + h * 64 + d]) * QSCALE;
                } else {
                    sA = bf2f(pb[PB_KSC + h * 64 + d]);
                    sB = bf2f(pb[PB_KBI + h * 64 + d]);
                }
                u16* dstbuf = (sec == 0) ? Qb : Kb;
                for (int r = 0; r < 4; r++) {
                    const int t = tbase + wm + mi * 16 + quad * 4 + r;
                    float v = (acc[mi][ni][r] + bv) * sA + sB;
                    dstbuf[(((size_t)(bb * NH_SZ + h)) * T_SZ + t) * HD_SZ + d] = f2bf(v);
                }
            }
        }
    }
}

// -------- Flash attention: block = (head, diagonal tile-pair), 8 waves -----
// Causal pairing: block p processes q-tiles (15-p) then (p): 34 k-iterations
// for EVERY block -> uniform makespan. 512 blocks = 2/CU.
// S^T formulation: mfma(K_frag, Q_frag) -> D[key][q]; each lane owns ONE
// q-row (q = l16): softmax max/sum are in-register + 2 cross-quad shuffles.
// PV as o^T[d][q] = mfma(V^T_frag, P^T_frag); Vs is already [d][key].
__global__ __launch_bounds__(512) void attn_k(const u16* __restrict__ Qb,
                                              const u16* __restrict__ Kb,
                                              const u16* __restrict__ Vtg,
                                              u16* __restrict__ Y) {
    __shared__ __align__(16) u16 Ks[64 * 72];       // [key][d]
    __shared__ __align__(16) u16 Vs[64 * 72];       // [d][key]
    __shared__ __align__(16) u16 Ps[8 * 16 * 88];   // per-wave P^T [q][key], stride 88
    const int blk = blockIdx.x;
    const int head = blk & 63;          // b*NH + h
    const int p = blk >> 6;             // pair index 0..7
    const int b = head >> 4, h = head & 15;
    const int tid = threadIdx.x, lane = tid & 63, w = tid >> 6;
    const int quad = lane >> 4, l16 = lane & 15;
    const size_t qk_off = (size_t)head * (T_SZ * HD_SZ);
    const size_t v_off = (size_t)head * (HD_SZ * T_SZ);
    u16* psw = &Ps[w * 1408];           // wave-private P^T region

    for (int tile = 0; tile < 2; tile++) {
        const int qt = tile ? p : (15 - p);
        const int q0 = qt * 128;
        const int rbase = q0 + w * 16;  // wave's first q row
        const int q = rbase + l16;      // this lane's q row

        // wave's Q block = 2 fragments (identical layout for A and B operands)
        const short8 aq0 = *(const short8*)&Qb[qk_off + (size_t)q * HD_SZ + quad * 8];
        const short8 aq1 = *(const short8*)&Qb[qk_off + (size_t)q * HD_SZ + 32 + quad * 8];

        floatx4 o[4];                   // o^T: col=q(lane), rows=d-group mi
        for (int mi = 0; mi < 4; mi++) o[mi] = 0.f;
        float m_run = -1e30f, l_run = 0.f;

        for (int k0 = 0; k0 < q0 + 128; k0 += 64) {
            __syncthreads();
            {
                int r = tid >> 3, c8 = (tid & 7) * 8;
                *(float4*)&Ks[r * 72 + c8] =
                    *(const float4*)&Kb[qk_off + (size_t)(k0 + r) * HD_SZ + c8];
                *(float4*)&Vs[r * 72 + c8] =
                    *(const float4*)&Vtg[v_off + (size_t)r * T_SZ + k0 + c8];
            }
            __syncthreads();
            if (k0 > rbase + 15) continue;  // fully masked for this wave

            // S^T[key][q]: A = K fragments, B = Q fragment
            floatx4 s[4];
            for (int ni = 0; ni < 4; ni++) s[ni] = 0.f;
            for (int ni = 0; ni < 4; ni++)
                s[ni] = __builtin_amdgcn_mfma_f32_16x16x32_bf16(
                    *(const short8*)&Ks[(ni * 16 + l16) * 72 + quad * 8], aq0, s[ni], 0, 0, 0);
            for (int ni = 0; ni < 4; ni++)
                s[ni] = __builtin_amdgcn_mfma_f32_16x16x32_bf16(
                    *(const short8*)&Ks[(ni * 16 + l16) * 72 + 32 + quad * 8], aq1, s[ni], 0, 0, 0);

            if (k0 + 63 > rbase) {          // tile touches the diagonal
                for (int ni = 0; ni < 4; ni++)
                    for (int r = 0; r < 4; r++) {
                        int key = k0 + ni * 16 + quad * 4 + r;
                        if (key > q) s[ni][r] = -1e30f;
                    }
            }

            // per-lane (single-q-row) online softmax
            float mx = s[0][0];
            for (int ni = 0; ni < 4; ni++)
                for (int r = 0; r < 4; r++) mx = fmaxf(mx, s[ni][r]);
            mx = fmaxf(mx, __shfl_xor(mx, 16, 64));
            mx = fmaxf(mx, __shfl_xor(mx, 32, 64));
            const float mnew = fmaxf(m_run, mx);
            const float alpha = exp2f(m_run - mnew);
            float rsum = 0.f;
            for (int ni = 0; ni < 4; ni++)
                for (int r = 0; r < 4; r++) {
                    float pv = exp2f(s[ni][r] - mnew);
                    s[ni][r] = pv;
                    rsum += pv;
                }
            rsum += __shfl_xor(rsum, 16, 64);
            rsum += __shfl_xor(rsum, 32, 64);
            m_run = mnew;
            l_run = l_run * alpha + rsum;
            for (int mi = 0; mi < 4; mi++) o[mi] *= alpha;

            // P^T -> wave-private LDS: 4x 8B stores, [q=l16][key] stride 88
            for (int ni = 0; ni < 4; ni++) {
                ushort4 pk;
                pk.x = f2bf(s[ni][0]); pk.y = f2bf(s[ni][1]);
                pk.z = f2bf(s[ni][2]); pk.w = f2bf(s[ni][3]);
                *(ushort4*)&psw[l16 * 88 + ni * 16 + quad * 4] = pk;
            }

            // o^T[d][q] += V^T * P^T
            for (int kk = 0; kk < 64; kk += 32) {
                short8 pfr = *(const short8*)&psw[l16 * 88 + kk + quad * 8];
                for (int mi = 0; mi < 4; mi++) {
                    short8 vfr = *(const short8*)&Vs[(mi * 16 + l16) * 72 + kk + quad * 8];
                    o[mi] = __builtin_amdgcn_mfma_f32_16x16x32_bf16(vfr, pfr, o[mi], 0, 0, 0);
                }
            }
        }

        // write y in [B,T,NH,HD]: lane's q row, 4 contiguous d per mi -> 8B stores
        const float inv = 1.0f / l_run;
        u16* yrow = &Y[(((size_t)b * T_SZ + q) * NH_SZ + h) * HD_SZ];
        for (int mi = 0; mi < 4; mi++) {
            ushort4 pk;
            pk.x = f2bf(o[mi][0] * inv); pk.y = f2bf(o[mi][1] * inv);
            pk.z = f2bf(o[mi][2] * inv); pk.w = f2bf(o[mi][3] * inv);
            *(ushort4*)&yrow[mi * 16 + quad * 4] = pk;
        }
    }
}

// ---------------- Proj GEMM: Y[8192,1024] @ Wt[1024,1024]^T + bias ---------
// m97-config BK=64 staging; output dtype branches on flag
__global__ __launch_bounds__(256) void proj_gemm(const u16* __restrict__ Yin,
                                                 const u16* __restrict__ Wt,
                                                 const u16* __restrict__ pb,
                                                 void* __restrict__ out,
                                                 const int* __restrict__ flag) {
    __shared__ __align__(16) u16 As[128 * 64];
    __shared__ __align__(16) u16 Bs[128 * 64];
    const int isf = flag[0];
    const int bm = blockIdx.y * 128, bn = blockIdx.x * 128;
    const int tid = threadIdx.x;
    const int lane = tid & 63, wave = tid >> 6;
    const int quad = lane >> 4, l16 = lane & 15;
    const int wm = (wave & 1) * 64, wn = (wave >> 1) * 64;
    const int lrow = lane >> 3, lcol = (lane & 7) * 8;

    floatx4 acc[4][4];
    for (int mi = 0; mi < 4; mi++)
        for (int ni = 0; ni < 4; ni++) acc[mi][ni] = 0.f;

    for (int k0 = 0; k0 < K_DIM; k0 += 64) {
        __syncthreads();
        for (int j = 0; j < 4; j++) {
            const int rb = wave * 32 + j * 8;
            gl_lds16(&Yin[(size_t)(bm + rb + lrow) * K_DIM + k0 + lcol], &As[rb * 64]);
            gl_lds16(&Wt[(size_t)(bn + rb + lrow) * K_DIM + k0 + lcol], &Bs[rb * 64]);
        }
        __syncthreads();
        for (int kk = 0; kk < 64; kk += 32) {
            short8 a[4], b[4];
            for (int mi = 0; mi < 4; mi++)
                a[mi] = *(const short8*)&As[(wm + mi * 16 + l16) * 64 + kk + quad * 8];
            for (int ni = 0; ni < 4; ni++)
                b[ni] = *(const short8*)&Bs[(wn + ni * 16 + l16) * 64 + kk + quad * 8];
            for (int mi = 0; mi < 4; mi++)
                for (int ni = 0; ni < 4; ni++)
                    acc[mi][ni] = __builtin_amdgcn_mfma_f32_16x16x32_bf16(
                        a[mi], b[ni], acc[mi][ni], 0, 0, 0);
        }
    }

    for (int mi = 0; mi < 4; mi++) {
        for (int ni = 0; ni < 4; ni++) {
            const int col = bn + wn + ni * 16 + l16;
            const float bv = bf2f(pb[PB_BPROJ + col]);
            for (int r = 0; r < 4; r++) {
                const int row = bm + wm + mi * 16 + quad * 4 + r;
                const float v = acc[mi][ni][r] + bv;
                if (isf) ((float*)out)[(size_t)row * C_SZ + col] = v;
                else     ((u16*)out)[(size_t)row * C_SZ + col] = f2bf(v);
            }
        }
    }
}

extern "C" void kernel_launch(void* const* d_in, const int* in_sizes, int n_in,
                              void* d_out, int out_size, void* d_ws, size_t ws_size,
                              hipStream_t stream) {
    const void* x     = d_in[0];
    const void* Wqkv  = d_in[1];
    const void* bqkv  = d_in[2];
    const void* Wproj = d_in[3];
    const void* bproj = d_in[4];
    const void* qsc   = d_in[5];
    const void* qbi   = d_in[6];
    const void* ksc   = d_in[7];
    const void* kbi   = d_in[8];

    u16* ws = (u16*)d_ws;
    int* flag    = (int*)d_ws;
    u16* xb      = ws + OFF_XB;
    u16* Wt_qkv  = ws + OFF_WQT;
    u16* Wt_proj = ws + OFF_WPT;
    u16* pb      = ws + OFF_PB;
    u16* Qb      = ws + OFF_Q;
    u16* Kb      = ws + OFF_K;
    u16* Vb      = ws + OFF_V;     // [B,NH,HD,T]
    u16* Yb      = ws + OFF_Y;

    detect_k<<<1, 256, 0, stream>>>((const u16*)x, flag);

    conv_copy_k<<<8192, 256, 0, stream>>>(x, xb, 2097152, flag);
    conv_params_k<<<8, 256, 0, stream>>>(bqkv, bproj, qsc, qbi, ksc, kbi, pb, flag);
    conv_transpose_k<<<dim3(96, 32), 256, 0, stream>>>(Wqkv, Wt_qkv, 1024, 3072, flag);
    conv_transpose_k<<<dim3(32, 32), 256, 0, stream>>>(Wproj, Wt_proj, 1024, 1024, flag);

    qkv_gemm<<<dim3(24, 64), 256, 0, stream>>>(xb, Wt_qkv, pb, Qb, Kb, Vb);
    attn_k<<<dim3(512), 512, 0, stream>>>(Qb, Kb, Vb, Yb);
    proj_gemm<<<dim3(8, 64), 256, 0, stream>>>(Yb, Wt_proj, pb, d_out, flag);
}

// Round 7
// 323.548 us; speedup vs baseline: 1.8522x; 1.0257x over previous
//
#include <hip/hip_runtime.h>
#include <hip/hip_bf16.h>

typedef unsigned short u16;
typedef __attribute__((ext_vector_type(8))) short short8;
typedef __attribute__((ext_vector_type(4))) float floatx4;

#define B_SZ 4
#define T_SZ 2048
#define C_SZ 1024
#define NH_SZ 16
#define HD_SZ 64
#define M_TOT 8192      // B*T
#define K_DIM 1024      // C

// fold softmax 1/sqrt(64) and log2(e) into Q's affine: scores land in log2 domain
#define QSCALE 0.1803368801111204f   // 0.125 * 1.4426950408889634

// workspace layout (u16 element offsets from ws base; all 16B-aligned)
#define OFF_XB   ((size_t)16)
#define OFF_WQT  (OFF_XB + 8388608)
#define OFF_WPT  (OFF_WQT + 3145728)
#define OFF_PB   (OFF_WPT + 1048576)
#define OFF_Q    (OFF_PB + 8192)
#define OFF_K    (OFF_Q + 8388608)
#define OFF_V    (OFF_K + 8388608)
#define OFF_Y    (OFF_V + 8388608)
// params sub-layout inside PB (contiguous: sources in order)
#define PB_BQKV  0
#define PB_BPROJ 3072
#define PB_QSC   4096
#define PB_QBI   5120
#define PB_KSC   6144
#define PB_KBI   7168

__device__ __forceinline__ float bf2f(u16 u) {
    return __uint_as_float(((unsigned)u) << 16);
}
__device__ __forceinline__ u16 f2bf(float f) {
    unsigned x = __float_as_uint(f);
    unsigned r = (x + 0x7fffu + ((x >> 16) & 1u)) >> 16;
    return (u16)r;
}
// async global->LDS, 16B per lane; LDS dest = wave-uniform base + lane*16
__device__ __forceinline__ void gl_lds16(const u16* g, u16* l) {
    __builtin_amdgcn_global_load_lds(
        (const __attribute__((address_space(1))) void*)g,
        (__attribute__((address_space(3))) void*)l, 16, 0, 0);
}

// ---- dtype detector: fp32 reinterpreted as bf16 has wild exponents --------
__global__ __launch_bounds__(256) void detect_k(const u16* __restrict__ x,
                                                int* __restrict__ flag) {
    __shared__ int cnt;
    if (threadIdx.x == 0) cnt = 0;
    __syncthreads();
    int bad = 0;
    for (int i = threadIdx.x; i < 512; i += 256) {
        float v = fabsf(bf2f(x[i]));
        if (v > 1024.0f || (v != 0.0f && v < 9.5367431640625e-7f)) bad++;
    }
    atomicAdd(&cnt, bad);
    __syncthreads();
    if (threadIdx.x == 0) flag[0] = (cnt > 16) ? 1 : 0;
}

// ---- normalize x to bf16 (copy or fp32->bf16) -----------------------------
__global__ __launch_bounds__(256) void conv_copy_k(const void* __restrict__ in,
                                                   u16* __restrict__ out, int n4,
                                                   const int* __restrict__ flag) {
    const int i = blockIdx.x * 256 + threadIdx.x;   // group of 4 elements
    if (i >= n4) return;
    if (flag[0]) {
        const float4 v = ((const float4*)in)[i];
        ushort4 o;
        o.x = f2bf(v.x); o.y = f2bf(v.y); o.z = f2bf(v.z); o.w = f2bf(v.w);
        ((ushort4*)out)[i] = o;
    } else {
        ((ushort4*)out)[i] = ((const ushort4*)in)[i];
    }
}

// ---- all small param arrays -> contiguous pb buffer in one launch ---------
__global__ __launch_bounds__(256) void conv_params_k(
        const void* __restrict__ bqkv, const void* __restrict__ bproj,
        const void* __restrict__ qsc, const void* __restrict__ qbi,
        const void* __restrict__ ksc, const void* __restrict__ kbi,
        u16* __restrict__ pb, const int* __restrict__ flag) {
    const int i4 = blockIdx.x * 256 + threadIdx.x;  // 0..2047
    if (i4 >= 2048) return;
    const int e = i4 * 4;
    const void* src; int off;
    if (e < 3072)      { src = bqkv;  off = e; }
    else if (e < 4096) { src = bproj; off = e - 3072; }
    else if (e < 5120) { src = qsc;   off = e - 4096; }
    else if (e < 6144) { src = qbi;   off = e - 5120; }
    else if (e < 7168) { src = ksc;   off = e - 6144; }
    else               { src = kbi;   off = e - 7168; }
    ushort4 o;
    if (flag[0]) {
        const float4 v = *(const float4*)((const float*)src + off);
        o.x = f2bf(v.x); o.y = f2bf(v.y); o.z = f2bf(v.z); o.w = f2bf(v.w);
    } else {
        o = *(const ushort4*)((const u16*)src + off);
    }
    *(ushort4*)&pb[e] = o;
}

// ---- weight transpose with dtype normalization: in [R][C] -> out [C][R] ---
__global__ __launch_bounds__(256) void conv_transpose_k(const void* __restrict__ in,
                                                        u16* __restrict__ out,
                                                        int R, int C,
                                                        const int* __restrict__ flag) {
    __shared__ u16 t[32][33];
    const int isf = flag[0];
    const int c0 = blockIdx.x * 32, r0 = blockIdx.y * 32;
    const int tx = threadIdx.x & 31, ty = threadIdx.x >> 5;  // ty in 0..7
    for (int i = 0; i < 4; i++) {
        int r = ty + i * 8;
        size_t idx = (size_t)(r0 + r) * C + c0 + tx;
        t[r][tx] = isf ? f2bf(((const float*)in)[idx]) : ((const u16*)in)[idx];
    }
    __syncthreads();
    for (int i = 0; i < 4; i++) {
        int cr = ty + i * 8;
        out[(size_t)(c0 + cr) * R + r0 + tx] = t[tx][cr];
    }
}

// ---------------- QKV GEMM: X[8192,1024] @ Wt[3072,1024]^T + bias ----------
// BK=64, global_load_lds width 16, XOR-chunk-swizzled LDS:
// LDS slot s of row r holds global chunk s ^ (r&7)  (chunk = 8 u16 = 16 B).
// Staging swizzles the SOURCE address (LDS dest is hw-fixed lane*16);
// reads pick slot ((kk>>3)+quad) ^ (l16&7) -> 8 dwords/bank (balanced).
__global__ __launch_bounds__(256) void qkv_gemm(
        const u16* __restrict__ X, const u16* __restrict__ Wt,
        const u16* __restrict__ pb,
        u16* __restrict__ Qb, u16* __restrict__ Kb, u16* __restrict__ Vb) {
    __shared__ __align__(16) u16 As[128 * 64];
    __shared__ __align__(16) u16 Bs[128 * 64];
    const int bm = blockIdx.y * 128, bn = blockIdx.x * 128;
    const int tid = threadIdx.x;
    const int lane = tid & 63, wave = tid >> 6;
    const int quad = lane >> 4, l16 = lane & 15;
    const int wm = (wave & 1) * 64, wn = (wave >> 1) * 64;
    const int lrow = lane >> 3;                       // 8 rows per inst
    const int lcol = ((lane & 7) ^ lrow) * 8;         // swizzled source chunk

    floatx4 acc[4][4];
    for (int mi = 0; mi < 4; mi++)
        for (int ni = 0; ni < 4; ni++) acc[mi][ni] = 0.f;

    for (int k0 = 0; k0 < K_DIM; k0 += 64) {
        __syncthreads();
        for (int j = 0; j < 4; j++) {
            const int rb = wave * 32 + j * 8;
            gl_lds16(&X[(size_t)(bm + rb + lrow) * K_DIM + k0 + lcol], &As[rb * 64]);
            gl_lds16(&Wt[(size_t)(bn + rb + lrow) * K_DIM + k0 + lcol], &Bs[rb * 64]);
        }
        __syncthreads();
        for (int kk = 0; kk < 64; kk += 32) {
            const int cb = kk >> 3;                   // 0 or 4
            const int slot = ((cb + quad) ^ (l16 & 7)) * 8;
            short8 a[4], b[4];
            for (int mi = 0; mi < 4; mi++)
                a[mi] = *(const short8*)&As[(wm + mi * 16 + l16) * 64 + slot];
            for (int ni = 0; ni < 4; ni++)
                b[ni] = *(const short8*)&Bs[(wn + ni * 16 + l16) * 64 + slot];
            for (int mi = 0; mi < 4; mi++)
                for (int ni = 0; ni < 4; ni++)
                    acc[mi][ni] = __builtin_amdgcn_mfma_f32_16x16x32_bf16(
                        a[mi], b[ni], acc[mi][ni], 0, 0, 0);
        }
    }

    const int sec = bn >> 10;  // 0=q 1=k 2=v (128-tile never crosses 1024)
    const int bb = bm >> 11;   // batch index (constant per block)
    const int tbase = bm & 2047;
    for (int mi = 0; mi < 4; mi++) {
        for (int ni = 0; ni < 4; ni++) {
            const int col = bn + wn + ni * 16 + l16;
            const int cmod = col & 1023;
            const int h = cmod >> 6, d = cmod & 63;
            const float bv = bf2f(pb[PB_BQKV + col]);
            if (sec == 2) {
                const int t0 = tbase + wm + mi * 16 + quad * 4;
                ushort4 pk;
                pk.x = f2bf(acc[mi][ni][0] + bv);
                pk.y = f2bf(acc[mi][ni][1] + bv);
                pk.z = f2bf(acc[mi][ni][2] + bv);
                pk.w = f2bf(acc[mi][ni][3] + bv);
                *(ushort4*)&Vb[(((size_t)(bb * NH_SZ + h)) * HD_SZ + d) * T_SZ + t0] = pk;
            } else {
                float sA, sB;
                if (sec == 0) {
                    sA = bf2f(pb[PB_QSC + h * 64 + d]) * QSCALE;
                    sB = bf2f(pb[PB_QBI + h * 64 + d]) * QSCALE;
                } else {
                    sA = bf2f(pb[PB_KSC + h * 64 + d]);
                    sB = bf2f(pb[PB_KBI + h * 64 + d]);
                }
                u16* dstbuf = (sec == 0) ? Qb : Kb;
                for (int r = 0; r < 4; r++) {
                    const int t = tbase + wm + mi * 16 + quad * 4 + r;
                    float v = (acc[mi][ni][r] + bv) * sA + sB;
                    dstbuf[(((size_t)(bb * NH_SZ + h)) * T_SZ + t) * HD_SZ + d] = f2bf(v);
                }
            }
        }
    }
}

// -------- Flash attention: block = (head, diagonal tile-pair), 8 waves -----
// Causal pairing: block p processes q-tiles (15-p) then (p): 34 k-iterations
// for EVERY block -> uniform makespan. 512 blocks = 2/CU.
// S^T formulation: mfma(K_frag, Q_frag) -> D[key][q]; each lane owns ONE
// q-row (q = l16): softmax max/sum are in-register + 2 cross-quad shuffles.
// PV as o^T[d][q] = mfma(V^T_frag, P^T_frag); Vs is already [d][key].
__global__ __launch_bounds__(512) void attn_k(const u16* __restrict__ Qb,
                                              const u16* __restrict__ Kb,
                                              const u16* __restrict__ Vtg,
                                              u16* __restrict__ Y) {
    __shared__ __align__(16) u16 Ks[64 * 72];       // [key][d]
    __shared__ __align__(16) u16 Vs[64 * 72];       // [d][key]
    __shared__ __align__(16) u16 Ps[8 * 16 * 88];   // per-wave P^T [q][key], stride 88
    const int blk = blockIdx.x;
    const int head = blk & 63;          // b*NH + h
    const int p = blk >> 6;             // pair index 0..7
    const int b = head >> 4, h = head & 15;
    const int tid = threadIdx.x, lane = tid & 63, w = tid >> 6;
    const int quad = lane >> 4, l16 = lane & 15;
    const size_t qk_off = (size_t)head * (T_SZ * HD_SZ);
    const size_t v_off = (size_t)head * (HD_SZ * T_SZ);
    u16* psw = &Ps[w * 1408];           // wave-private P^T region

    for (int tile = 0; tile < 2; tile++) {
        const int qt = tile ? p : (15 - p);
        const int q0 = qt * 128;
        const int rbase = q0 + w * 16;  // wave's first q row
        const int q = rbase + l16;      // this lane's q row

        // wave's Q block = 2 fragments (identical layout for A and B operands)
        const short8 aq0 = *(const short8*)&Qb[qk_off + (size_t)q * HD_SZ + quad * 8];
        const short8 aq1 = *(const short8*)&Qb[qk_off + (size_t)q * HD_SZ + 32 + quad * 8];

        floatx4 o[4];                   // o^T: col=q(lane), rows=d-group mi
        for (int mi = 0; mi < 4; mi++) o[mi] = 0.f;
        float m_run = -1e30f, l_run = 0.f;

        for (int k0 = 0; k0 < q0 + 128; k0 += 64) {
            __syncthreads();
            {
                int r = tid >> 3, c8 = (tid & 7) * 8;
                *(float4*)&Ks[r * 72 + c8] =
                    *(const float4*)&Kb[qk_off + (size_t)(k0 + r) * HD_SZ + c8];
                *(float4*)&Vs[r * 72 + c8] =
                    *(const float4*)&Vtg[v_off + (size_t)r * T_SZ + k0 + c8];
            }
            __syncthreads();
            if (k0 > rbase + 15) continue;  // fully masked for this wave

            // S^T[key][q]: A = K fragments, B = Q fragment
            floatx4 s[4];
            for (int ni = 0; ni < 4; ni++) s[ni] = 0.f;
            for (int ni = 0; ni < 4; ni++)
                s[ni] = __builtin_amdgcn_mfma_f32_16x16x32_bf16(
                    *(const short8*)&Ks[(ni * 16 + l16) * 72 + quad * 8], aq0, s[ni], 0, 0, 0);
            for (int ni = 0; ni < 4; ni++)
                s[ni] = __builtin_amdgcn_mfma_f32_16x16x32_bf16(
                    *(const short8*)&Ks[(ni * 16 + l16) * 72 + 32 + quad * 8], aq1, s[ni], 0, 0, 0);

            if (k0 + 63 > rbase) {          // tile touches the diagonal
                for (int ni = 0; ni < 4; ni++)
                    for (int r = 0; r < 4; r++) {
                        int key = k0 + ni * 16 + quad * 4 + r;
                        if (key > q) s[ni][r] = -1e30f;
                    }
            }

            // per-lane (single-q-row) online softmax
            float mx = s[0][0];
            for (int ni = 0; ni < 4; ni++)
                for (int r = 0; r < 4; r++) mx = fmaxf(mx, s[ni][r]);
            mx = fmaxf(mx, __shfl_xor(mx, 16, 64));
            mx = fmaxf(mx, __shfl_xor(mx, 32, 64));
            const float mnew = fmaxf(m_run, mx);
            const float alpha = exp2f(m_run - mnew);
            float rsum = 0.f;
            for (int ni = 0; ni < 4; ni++)
                for (int r = 0; r < 4; r++) {
                    float pv = exp2f(s[ni][r] - mnew);
                    s[ni][r] = pv;
                    rsum += pv;
                }
            rsum += __shfl_xor(rsum, 16, 64);
            rsum += __shfl_xor(rsum, 32, 64);
            m_run = mnew;
            l_run = l_run * alpha + rsum;
            for (int mi = 0; mi < 4; mi++) o[mi] *= alpha;

            // P^T -> wave-private LDS: 4x 8B stores, [q=l16][key] stride 88
            for (int ni = 0; ni < 4; ni++) {
                ushort4 pk;
                pk.x = f2bf(s[ni][0]); pk.y = f2bf(s[ni][1]);
                pk.z = f2bf(s[ni][2]); pk.w = f2bf(s[ni][3]);
                *(ushort4*)&psw[l16 * 88 + ni * 16 + quad * 4] = pk;
            }

            // o^T[d][q] += V^T * P^T
            for (int kk = 0; kk < 64; kk += 32) {
                short8 pfr = *(const short8*)&psw[l16 * 88 + kk + quad * 8];
                for (int mi = 0; mi < 4; mi++) {
                    short8 vfr = *(const short8*)&Vs[(mi * 16 + l16) * 72 + kk + quad * 8];
                    o[mi] = __builtin_amdgcn_mfma_f32_16x16x32_bf16(vfr, pfr, o[mi], 0, 0, 0);
                }
            }
        }

        // write y in [B,T,NH,HD]: lane's q row, 4 contiguous d per mi -> 8B stores
        const float inv = 1.0f / l_run;
        u16* yrow = &Y[(((size_t)b * T_SZ + q) * NH_SZ + h) * HD_SZ];
        for (int mi = 0; mi < 4; mi++) {
            ushort4 pk;
            pk.x = f2bf(o[mi][0] * inv); pk.y = f2bf(o[mi][1] * inv);
            pk.z = f2bf(o[mi][2] * inv); pk.w = f2bf(o[mi][3] * inv);
            *(ushort4*)&yrow[mi * 16 + quad * 4] = pk;
        }
    }
}

// ---------------- Proj GEMM: Y[8192,1024] @ Wt[1024,1024]^T + bias ---------
// BK=64 XOR-swizzled staging; output dtype branches on flag
__global__ __launch_bounds__(256) void proj_gemm(const u16* __restrict__ Yin,
                                                 const u16* __restrict__ Wt,
                                                 const u16* __restrict__ pb,
                                                 void* __restrict__ out,
                                                 const int* __restrict__ flag) {
    __shared__ __align__(16) u16 As[128 * 64];
    __shared__ __align__(16) u16 Bs[128 * 64];
    const int isf = flag[0];
    const int bm = blockIdx.y * 128, bn = blockIdx.x * 128;
    const int tid = threadIdx.x;
    const int lane = tid & 63, wave = tid >> 6;
    const int quad = lane >> 4, l16 = lane & 15;
    const int wm = (wave & 1) * 64, wn = (wave >> 1) * 64;
    const int lrow = lane >> 3;
    const int lcol = ((lane & 7) ^ lrow) * 8;         // swizzled source chunk

    floatx4 acc[4][4];
    for (int mi = 0; mi < 4; mi++)
        for (int ni = 0; ni < 4; ni++) acc[mi][ni] = 0.f;

    for (int k0 = 0; k0 < K_DIM; k0 += 64) {
        __syncthreads();
        for (int j = 0; j < 4; j++) {
            const int rb = wave * 32 + j * 8;
            gl_lds16(&Yin[(size_t)(bm + rb + lrow) * K_DIM + k0 + lcol], &As[rb * 64]);
            gl_lds16(&Wt[(size_t)(bn + rb + lrow) * K_DIM + k0 + lcol], &Bs[rb * 64]);
        }
        __syncthreads();
        for (int kk = 0; kk < 64; kk += 32) {
            const int cb = kk >> 3;
            const int slot = ((cb + quad) ^ (l16 & 7)) * 8;
            short8 a[4], b[4];
            for (int mi = 0; mi < 4; mi++)
                a[mi] = *(const short8*)&As[(wm + mi * 16 + l16) * 64 + slot];
            for (int ni = 0; ni < 4; ni++)
                b[ni] = *(const short8*)&Bs[(wn + ni * 16 + l16) * 64 + slot];
            for (int mi = 0; mi < 4; mi++)
                for (int ni = 0; ni < 4; ni++)
                    acc[mi][ni] = __builtin_amdgcn_mfma_f32_16x16x32_bf16(
                        a[mi], b[ni], acc[mi][ni], 0, 0, 0);
        }
    }

    for (int mi = 0; mi < 4; mi++) {
        for (int ni = 0; ni < 4; ni++) {
            const int col = bn + wn + ni * 16 + l16;
            const float bv = bf2f(pb[PB_BPROJ + col]);
            for (int r = 0; r < 4; r++) {
                const int row = bm + wm + mi * 16 + quad * 4 + r;
                const float v = acc[mi][ni][r] + bv;
                if (isf) ((float*)out)[(size_t)row * C_SZ + col] = v;
                else     ((u16*)out)[(size_t)row * C_SZ + col] = f2bf(v);
            }
        }
    }
}

extern "C" void kernel_launch(void* const* d_in, const int* in_sizes, int n_in,
                              void* d_out, int out_size, void* d_ws, size_t ws_size,
                              hipStream_t stream) {
    const void* x     = d_in[0];
    const void* Wqkv  = d_in[1];
    const void* bqkv  = d_in[2];
    const void* Wproj = d_in[3];
    const void* bproj = d_in[4];
    const void* qsc   = d_in[5];
    const void* qbi   = d_in[6];
    const void* ksc   = d_in[7];
    const void* kbi   = d_in[8];

    u16* ws = (u16*)d_ws;
    int* flag    = (int*)d_ws;
    u16* xb      = ws + OFF_XB;
    u16* Wt_qkv  = ws + OFF_WQT;
    u16* Wt_proj = ws + OFF_WPT;
    u16* pb      = ws + OFF_PB;
    u16* Qb      = ws + OFF_Q;
    u16* Kb      = ws + OFF_K;
    u16* Vb      = ws + OFF_V;     // [B,NH,HD,T]
    u16* Yb      = ws + OFF_Y;

    detect_k<<<1, 256, 0, stream>>>((const u16*)x, flag);

    conv_copy_k<<<8192, 256, 0, stream>>>(x, xb, 2097152, flag);
    conv_params_k<<<8, 256, 0, stream>>>(bqkv, bproj, qsc, qbi, ksc, kbi, pb, flag);
    conv_transpose_k<<<dim3(96, 32), 256, 0, stream>>>(Wqkv, Wt_qkv, 1024, 3072, flag);
    conv_transpose_k<<<dim3(32, 32), 256, 0, stream>>>(Wproj, Wt_proj, 1024, 1024, flag);

    qkv_gemm<<<dim3(24, 64), 256, 0, stream>>>(xb, Wt_qkv, pb, Qb, Kb, Vb);
    attn_k<<<dim3(512), 512, 0, stream>>>(Qb, Kb, Vb, Yb);
    proj_gemm<<<dim3(8, 64), 256, 0, stream>>>(Yb, Wt_proj, pb, d_out, flag);
}

// Round 8
// 316.959 us; speedup vs baseline: 1.8907x; 1.0208x over previous
//
#include <hip/hip_runtime.h>
#include <hip/hip_bf16.h>

typedef unsigned short u16;
typedef __attribute__((ext_vector_type(8))) short short8;
typedef __attribute__((ext_vector_type(4))) float floatx4;

#define B_SZ 4
#define T_SZ 2048
#define C_SZ 1024
#define NH_SZ 16
#define HD_SZ 64
#define M_TOT 8192      // B*T
#define K_DIM 1024      // C

// fold softmax 1/sqrt(64) and log2(e) into Q's affine: scores land in log2 domain
#define QSCALE 0.1803368801111204f   // 0.125 * 1.4426950408889634

// workspace layout (u16 element offsets from ws base; all 16B-aligned)
#define OFF_XB   ((size_t)16)
#define OFF_WQT  (OFF_XB + 8388608)
#define OFF_WPT  (OFF_WQT + 3145728)
#define OFF_PB   (OFF_WPT + 1048576)
#define OFF_Q    (OFF_PB + 8192)
#define OFF_K    (OFF_Q + 8388608)
#define OFF_V    (OFF_K + 8388608)
#define OFF_Y    (OFF_V + 8388608)
// params sub-layout inside PB (contiguous: sources in order)
#define PB_BQKV  0
#define PB_BPROJ 3072
#define PB_QSC   4096
#define PB_QBI   5120
#define PB_KSC   6144
#define PB_KBI   7168

__device__ __forceinline__ float bf2f(u16 u) {
    return __uint_as_float(((unsigned)u) << 16);
}
__device__ __forceinline__ u16 f2bf(float f) {          // round-nearest-even
    unsigned x = __float_as_uint(f);
    unsigned r = (x + 0x7fffu + ((x >> 16) & 1u)) >> 16;
    return (u16)r;
}
__device__ __forceinline__ u16 f2bf_fast(float f) {     // round-half-up (cheap)
    return (u16)((__float_as_uint(f) + 0x8000u) >> 16);
}
// async global->LDS, 16B per lane; LDS dest = wave-uniform base + lane*16
__device__ __forceinline__ void gl_lds16(const u16* g, u16* l) {
    __builtin_amdgcn_global_load_lds(
        (const __attribute__((address_space(1))) void*)g,
        (__attribute__((address_space(3))) void*)l, 16, 0, 0);
}

// ---- dtype detector: fp32 reinterpreted as bf16 has wild exponents --------
__global__ __launch_bounds__(256) void detect_k(const u16* __restrict__ x,
                                                int* __restrict__ flag) {
    __shared__ int cnt;
    if (threadIdx.x == 0) cnt = 0;
    __syncthreads();
    int bad = 0;
    for (int i = threadIdx.x; i < 512; i += 256) {
        float v = fabsf(bf2f(x[i]));
        if (v > 1024.0f || (v != 0.0f && v < 9.5367431640625e-7f)) bad++;
    }
    atomicAdd(&cnt, bad);
    __syncthreads();
    if (threadIdx.x == 0) flag[0] = (cnt > 16) ? 1 : 0;
}

// ---- normalize x to bf16 (copy or fp32->bf16) -----------------------------
__global__ __launch_bounds__(256) void conv_copy_k(const void* __restrict__ in,
                                                   u16* __restrict__ out, int n4,
                                                   const int* __restrict__ flag) {
    const int i = blockIdx.x * 256 + threadIdx.x;   // group of 4 elements
    if (i >= n4) return;
    if (flag[0]) {
        const float4 v = ((const float4*)in)[i];
        ushort4 o;
        o.x = f2bf(v.x); o.y = f2bf(v.y); o.z = f2bf(v.z); o.w = f2bf(v.w);
        ((ushort4*)out)[i] = o;
    } else {
        ((ushort4*)out)[i] = ((const ushort4*)in)[i];
    }
}

// ---- all small param arrays -> contiguous pb buffer in one launch ---------
__global__ __launch_bounds__(256) void conv_params_k(
        const void* __restrict__ bqkv, const void* __restrict__ bproj,
        const void* __restrict__ qsc, const void* __restrict__ qbi,
        const void* __restrict__ ksc, const void* __restrict__ kbi,
        u16* __restrict__ pb, const int* __restrict__ flag) {
    const int i4 = blockIdx.x * 256 + threadIdx.x;  // 0..2047
    if (i4 >= 2048) return;
    const int e = i4 * 4;
    const void* src; int off;
    if (e < 3072)      { src = bqkv;  off = e; }
    else if (e < 4096) { src = bproj; off = e - 3072; }
    else if (e < 5120) { src = qsc;   off = e - 4096; }
    else if (e < 6144) { src = qbi;   off = e - 5120; }
    else if (e < 7168) { src = ksc;   off = e - 6144; }
    else               { src = kbi;   off = e - 7168; }
    ushort4 o;
    if (flag[0]) {
        const float4 v = *(const float4*)((const float*)src + off);
        o.x = f2bf(v.x); o.y = f2bf(v.y); o.z = f2bf(v.z); o.w = f2bf(v.w);
    } else {
        o = *(const ushort4*)((const u16*)src + off);
    }
    *(ushort4*)&pb[e] = o;
}

// ---- weight transpose with dtype normalization: in [R][C] -> out [C][R] ---
__global__ __launch_bounds__(256) void conv_transpose_k(const void* __restrict__ in,
                                                        u16* __restrict__ out,
                                                        int R, int C,
                                                        const int* __restrict__ flag) {
    __shared__ u16 t[32][33];
    const int isf = flag[0];
    const int c0 = blockIdx.x * 32, r0 = blockIdx.y * 32;
    const int tx = threadIdx.x & 31, ty = threadIdx.x >> 5;  // ty in 0..7
    for (int i = 0; i < 4; i++) {
        int r = ty + i * 8;
        size_t idx = (size_t)(r0 + r) * C + c0 + tx;
        t[r][tx] = isf ? f2bf(((const float*)in)[idx]) : ((const u16*)in)[idx];
    }
    __syncthreads();
    for (int i = 0; i < 4; i++) {
        int cr = ty + i * 8;
        out[(size_t)(c0 + cr) * R + r0 + tx] = t[tx][cr];
    }
}

// ---------------- QKV GEMM: X[8192,1024] @ Wt[3072,1024]^T + bias ----------
// BK=64, global_load_lds width 16, XOR-chunk-swizzled LDS.
__global__ __launch_bounds__(256) void qkv_gemm(
        const u16* __restrict__ X, const u16* __restrict__ Wt,
        const u16* __restrict__ pb,
        u16* __restrict__ Qb, u16* __restrict__ Kb, u16* __restrict__ Vb) {
    __shared__ __align__(16) u16 As[128 * 64];
    __shared__ __align__(16) u16 Bs[128 * 64];
    const int bm = blockIdx.y * 128, bn = blockIdx.x * 128;
    const int tid = threadIdx.x;
    const int lane = tid & 63, wave = tid >> 6;
    const int quad = lane >> 4, l16 = lane & 15;
    const int wm = (wave & 1) * 64, wn = (wave >> 1) * 64;
    const int lrow = lane >> 3;                       // 8 rows per inst
    const int lcol = ((lane & 7) ^ lrow) * 8;         // swizzled source chunk

    floatx4 acc[4][4];
    for (int mi = 0; mi < 4; mi++)
        for (int ni = 0; ni < 4; ni++) acc[mi][ni] = 0.f;

    for (int k0 = 0; k0 < K_DIM; k0 += 64) {
        __syncthreads();
        for (int j = 0; j < 4; j++) {
            const int rb = wave * 32 + j * 8;
            gl_lds16(&X[(size_t)(bm + rb + lrow) * K_DIM + k0 + lcol], &As[rb * 64]);
            gl_lds16(&Wt[(size_t)(bn + rb + lrow) * K_DIM + k0 + lcol], &Bs[rb * 64]);
        }
        __syncthreads();
        for (int kk = 0; kk < 64; kk += 32) {
            const int cb = kk >> 3;                   // 0 or 4
            const int slot = ((cb + quad) ^ (l16 & 7)) * 8;
            short8 a[4], b[4];
            for (int mi = 0; mi < 4; mi++)
                a[mi] = *(const short8*)&As[(wm + mi * 16 + l16) * 64 + slot];
            for (int ni = 0; ni < 4; ni++)
                b[ni] = *(const short8*)&Bs[(wn + ni * 16 + l16) * 64 + slot];
            for (int mi = 0; mi < 4; mi++)
                for (int ni = 0; ni < 4; ni++)
                    acc[mi][ni] = __builtin_amdgcn_mfma_f32_16x16x32_bf16(
                        a[mi], b[ni], acc[mi][ni], 0, 0, 0);
        }
    }

    const int sec = bn >> 10;  // 0=q 1=k 2=v (128-tile never crosses 1024)
    const int bb = bm >> 11;   // batch index (constant per block)
    const int tbase = bm & 2047;
    for (int mi = 0; mi < 4; mi++) {
        for (int ni = 0; ni < 4; ni++) {
            const int col = bn + wn + ni * 16 + l16;
            const int cmod = col & 1023;
            const int h = cmod >> 6, d = cmod & 63;
            const float bv = bf2f(pb[PB_BQKV + col]);
            if (sec == 2) {
                const int t0 = tbase + wm + mi * 16 + quad * 4;
                ushort4 pk;
                pk.x = f2bf(acc[mi][ni][0] + bv);
                pk.y = f2bf(acc[mi][ni][1] + bv);
                pk.z = f2bf(acc[mi][ni][2] + bv);
                pk.w = f2bf(acc[mi][ni][3] + bv);
                *(ushort4*)&Vb[(((size_t)(bb * NH_SZ + h)) * HD_SZ + d) * T_SZ + t0] = pk;
            } else {
                float sA, sB;
                if (sec == 0) {
                    sA = bf2f(pb[PB_QSC + h * 64 + d]) * QSCALE;
                    sB = bf2f(pb[PB_QBI + h * 64 + d]) * QSCALE;
                } else {
                    sA = bf2f(pb[PB_KSC + h * 64 + d]);
                    sB = bf2f(pb[PB_KBI + h * 64 + d]);
                }
                u16* dstbuf = (sec == 0) ? Qb : Kb;
                for (int r = 0; r < 4; r++) {
                    const int t = tbase + wm + mi * 16 + quad * 4 + r;
                    float v = (acc[mi][ni][r] + bv) * sA + sB;
                    dstbuf[(((size_t)(bb * NH_SZ + h)) * T_SZ + t) * HD_SZ + d] = f2bf(v);
                }
            }
        }
    }
}

// -------- Flash attention: block = (head, diagonal tile-pair), 8 waves -----
// Uniform makespan pairing (34 k-iters/block). S^T formulation (lane owns one
// q-row). K/V staged via global_load_lds + XOR chunk swizzle (stride 64, no
// pad, balanced banks). Row-sum via ones-MFMA (no sum tree / no shuffles).
// Cheap round-half-up bf16 converts in the hot loop.
__global__ __launch_bounds__(512) void attn_k(const u16* __restrict__ Qb,
                                              const u16* __restrict__ Kb,
                                              const u16* __restrict__ Vtg,
                                              u16* __restrict__ Y) {
    __shared__ __align__(16) u16 Ks[64 * 64];       // [key][d], swizzled chunks
    __shared__ __align__(16) u16 Vs[64 * 64];       // [d][key], swizzled chunks
    __shared__ __align__(16) u16 Ps[8 * 16 * 88];   // per-wave P^T [q][key], stride 88
    const int blk = blockIdx.x;
    const int head = blk & 63;          // b*NH + h
    const int p = blk >> 6;             // pair index 0..7
    const int b = head >> 4, h = head & 15;
    const int tid = threadIdx.x, lane = tid & 63, w = tid >> 6;
    const int quad = lane >> 4, l16 = lane & 15;
    const size_t qk_off = (size_t)head * (T_SZ * HD_SZ);
    const size_t v_off = (size_t)head * (HD_SZ * T_SZ);
    u16* psw = &Ps[w * 1408];           // wave-private P^T region
    const int lr = lane >> 3;                     // staging row within wave group
    const int lc = ((lane & 7) ^ lr) * 8;         // swizzled source chunk
    // read slots (loop-invariant): logical chunk (kk>>3)+quad of row r -> slot ^(r&7)
    const int sl0 = ((quad) ^ (l16 & 7)) * 8;         // kk = 0
    const int sl1 = ((4 + quad) ^ (l16 & 7)) * 8;     // kk = 32

    short8 ones;
    for (int j = 0; j < 8; j++) ones[j] = (short)0x3F80;  // bf16 1.0

    for (int tile = 0; tile < 2; tile++) {
        const int qt = tile ? p : (15 - p);
        const int q0 = qt * 128;
        const int rbase = q0 + w * 16;  // wave's first q row
        const int q = rbase + l16;      // this lane's q row

        // wave's Q block = 2 fragments (identical layout for A and B operands)
        const short8 aq0 = *(const short8*)&Qb[qk_off + (size_t)q * HD_SZ + quad * 8];
        const short8 aq1 = *(const short8*)&Qb[qk_off + (size_t)q * HD_SZ + 32 + quad * 8];

        floatx4 o[4];                   // o^T: col=q(lane), rows=d-group mi
        for (int mi = 0; mi < 4; mi++) o[mi] = 0.f;
        float m_run = -1e30f, l_run = 0.f;

        for (int k0 = 0; k0 < q0 + 128; k0 += 64) {
            __syncthreads();
            // wave w stages K rows 8w..8w+7 and V rows 8w..8w+7 (1KB each)
            gl_lds16(&Kb[qk_off + (size_t)(k0 + w * 8 + lr) * HD_SZ + lc], &Ks[w * 512]);
            gl_lds16(&Vtg[v_off + (size_t)(w * 8 + lr) * T_SZ + k0 + lc], &Vs[w * 512]);
            __syncthreads();
            if (k0 > rbase + 15) continue;  // fully masked for this wave

            // S^T[key][q]: A = K fragments, B = Q fragment
            floatx4 s[4];
            for (int ni = 0; ni < 4; ni++) s[ni] = 0.f;
            for (int ni = 0; ni < 4; ni++)
                s[ni] = __builtin_amdgcn_mfma_f32_16x16x32_bf16(
                    *(const short8*)&Ks[(ni * 16 + l16) * 64 + sl0], aq0, s[ni], 0, 0, 0);
            for (int ni = 0; ni < 4; ni++)
                s[ni] = __builtin_amdgcn_mfma_f32_16x16x32_bf16(
                    *(const short8*)&Ks[(ni * 16 + l16) * 64 + sl1], aq1, s[ni], 0, 0, 0);

            if (k0 + 63 > rbase) {          // tile touches the diagonal
                for (int ni = 0; ni < 4; ni++)
                    for (int r = 0; r < 4; r++) {
                        int key = k0 + ni * 16 + quad * 4 + r;
                        if (key > q) s[ni][r] = -1e30f;
                    }
            }

            // per-lane online softmax: max tree + 2 cross-quad shuffles
            float mx = fmaxf(fmaxf(s[0][0], s[0][1]), fmaxf(s[0][2], s[0][3]));
            for (int ni = 1; ni < 4; ni++)
                mx = fmaxf(mx, fmaxf(fmaxf(s[ni][0], s[ni][1]),
                                     fmaxf(s[ni][2], s[ni][3])));
            mx = fmaxf(mx, __shfl_xor(mx, 16, 64));
            mx = fmaxf(mx, __shfl_xor(mx, 32, 64));
            const float mnew = fmaxf(m_run, mx);
            const float alpha = exp2f(m_run - mnew);
            for (int ni = 0; ni < 4; ni++)
                for (int r = 0; r < 4; r++)
                    s[ni][r] = exp2f(s[ni][r] - mnew);
            m_run = mnew;
            for (int mi = 0; mi < 4; mi++) o[mi] *= alpha;

            // P^T -> wave-private LDS: 4x 8B stores (cheap half-up rounding)
            for (int ni = 0; ni < 4; ni++) {
                ushort4 pk;
                pk.x = f2bf_fast(s[ni][0]); pk.y = f2bf_fast(s[ni][1]);
                pk.z = f2bf_fast(s[ni][2]); pk.w = f2bf_fast(s[ni][3]);
                *(ushort4*)&psw[l16 * 88 + ni * 16 + quad * 4] = pk;
            }

            // o^T[d][q] += V^T * P^T;  row-sum via ones-MFMA (all regs = sum)
            floatx4 s4 = 0.f;
            for (int kk = 0; kk < 64; kk += 32) {
                const int sl = (kk == 0) ? 0 : 0;  // placeholder, slots below
                short8 pfr = *(const short8*)&psw[l16 * 88 + kk + quad * 8];
                const int vsl = (kk == 0) ? sl0 : sl1;
                s4 = __builtin_amdgcn_mfma_f32_16x16x32_bf16(ones, pfr, s4, 0, 0, 0);
                for (int mi = 0; mi < 4; mi++) {
                    short8 vfr = *(const short8*)&Vs[(mi * 16 + l16) * 64 + vsl];
                    o[mi] = __builtin_amdgcn_mfma_f32_16x16x32_bf16(vfr, pfr, o[mi], 0, 0, 0);
                }
                (void)sl;
            }
            l_run = l_run * alpha + s4[0];
        }

        // write y in [B,T,NH,HD]: lane's q row, 4 contiguous d per mi -> 8B stores
        const float inv = 1.0f / l_run;
        u16* yrow = &Y[(((size_t)b * T_SZ + q) * NH_SZ + h) * HD_SZ];
        for (int mi = 0; mi < 4; mi++) {
            ushort4 pk;
            pk.x = f2bf_fast(o[mi][0] * inv); pk.y = f2bf_fast(o[mi][1] * inv);
            pk.z = f2bf_fast(o[mi][2] * inv); pk.w = f2bf_fast(o[mi][3] * inv);
            *(ushort4*)&yrow[mi * 16 + quad * 4] = pk;
        }
    }
}

// ---------------- Proj GEMM: Y[8192,1024] @ Wt[1024,1024]^T + bias ---------
// BK=64 XOR-swizzled staging; output dtype branches on flag
__global__ __launch_bounds__(256) void proj_gemm(const u16* __restrict__ Yin,
                                                 const u16* __restrict__ Wt,
                                                 const u16* __restrict__ pb,
                                                 void* __restrict__ out,
                                                 const int* __restrict__ flag) {
    __shared__ __align__(16) u16 As[128 * 64];
    __shared__ __align__(16) u16 Bs[128 * 64];
    const int isf = flag[0];
    const int bm = blockIdx.y * 128, bn = blockIdx.x * 128;
    const int tid = threadIdx.x;
    const int lane = tid & 63, wave = tid >> 6;
    const int quad = lane >> 4, l16 = lane & 15;
    const int wm = (wave & 1) * 64, wn = (wave >> 1) * 64;
    const int lrow = lane >> 3;
    const int lcol = ((lane & 7) ^ lrow) * 8;         // swizzled source chunk

    floatx4 acc[4][4];
    for (int mi = 0; mi < 4; mi++)
        for (int ni = 0; ni < 4; ni++) acc[mi][ni] = 0.f;

    for (int k0 = 0; k0 < K_DIM; k0 += 64) {
        __syncthreads();
        for (int j = 0; j < 4; j++) {
            const int rb = wave * 32 + j * 8;
            gl_lds16(&Yin[(size_t)(bm + rb + lrow) * K_DIM + k0 + lcol], &As[rb * 64]);
            gl_lds16(&Wt[(size_t)(bn + rb + lrow) * K_DIM + k0 + lcol], &Bs[rb * 64]);
        }
        __syncthreads();
        for (int kk = 0; kk < 64; kk += 32) {
            const int cb = kk >> 3;
            const int slot = ((cb + quad) ^ (l16 & 7)) * 8;
            short8 a[4], b[4];
            for (int mi = 0; mi < 4; mi++)
                a[mi] = *(const short8*)&As[(wm + mi * 16 + l16) * 64 + slot];
            for (int ni = 0; ni < 4; ni++)
                b[ni] = *(const short8*)&Bs[(wn + ni * 16 + l16) * 64 + slot];
            for (int mi = 0; mi < 4; mi++)
                for (int ni = 0; ni < 4; ni++)
                    acc[mi][ni] = __builtin_amdgcn_mfma_f32_16x16x32_bf16(
                        a[mi], b[ni], acc[mi][ni], 0, 0, 0);
        }
    }

    for (int mi = 0; mi < 4; mi++) {
        for (int ni = 0; ni < 4; ni++) {
            const int col = bn + wn + ni * 16 + l16;
            const float bv = bf2f(pb[PB_BPROJ + col]);
            for (int r = 0; r < 4; r++) {
                const int row = bm + wm + mi * 16 + quad * 4 + r;
                const float v = acc[mi][ni][r] + bv;
                if (isf) ((float*)out)[(size_t)row * C_SZ + col] = v;
                else     ((u16*)out)[(size_t)row * C_SZ + col] = f2bf(v);
            }
        }
    }
}

extern "C" void kernel_launch(void* const* d_in, const int* in_sizes, int n_in,
                              void* d_out, int out_size, void* d_ws, size_t ws_size,
                              hipStream_t stream) {
    const void* x     = d_in[0];
    const void* Wqkv  = d_in[1];
    const void* bqkv  = d_in[2];
    const void* Wproj = d_in[3];
    const void* bproj = d_in[4];
    const void* qsc   = d_in[5];
    const void* qbi   = d_in[6];
    const void* ksc   = d_in[7];
    const void* kbi   = d_in[8];

    u16* ws = (u16*)d_ws;
    int* flag    = (int*)d_ws;
    u16* xb      = ws + OFF_XB;
    u16* Wt_qkv  = ws + OFF_WQT;
    u16* Wt_proj = ws + OFF_WPT;
    u16* pb      = ws + OFF_PB;
    u16* Qb      = ws + OFF_Q;
    u16* Kb      = ws + OFF_K;
    u16* Vb      = ws + OFF_V;     // [B,NH,HD,T]
    u16* Yb      = ws + OFF_Y;

    detect_k<<<1, 256, 0, stream>>>((const u16*)x, flag);

    conv_copy_k<<<8192, 256, 0, stream>>>(x, xb, 2097152, flag);
    conv_params_k<<<8, 256, 0, stream>>>(bqkv, bproj, qsc, qbi, ksc, kbi, pb, flag);
    conv_transpose_k<<<dim3(96, 32), 256, 0, stream>>>(Wqkv, Wt_qkv, 1024, 3072, flag);
    conv_transpose_k<<<dim3(32, 32), 256, 0, stream>>>(Wproj, Wt_proj, 1024, 1024, flag);

    qkv_gemm<<<dim3(24, 64), 256, 0, stream>>>(xb, Wt_qkv, pb, Qb, Kb, Vb);
    attn_k<<<dim3(512), 512, 0, stream>>>(Qb, Kb, Vb, Yb);
    proj_gemm<<<dim3(8, 64), 256, 0, stream>>>(Yb, Wt_proj, pb, d_out, flag);
}